// Round 11
// baseline (258.211 us; speedup 1.0000x reference)
//
#include <hip/hip_runtime.h>
#include <math.h>

#define T_  16
#define DB2_ 512
#define H_  512
#define Hh_ 256
#define U_  1024
#define MC_ 8
#define MT_ 4
#define L_  64
#define K_  64
#define M_  (T_*U_)   // 16384

#define BM 64
#define BNG 64
#define BK 64
#define S0_ (768*512)
#define S1_ (768*256)
#define WB_ (512*512)
#define KE_ (64*512)

typedef __attribute__((ext_vector_type(8))) short bf16x8;
typedef __attribute__((ext_vector_type(4))) float f32x4;

__device__ __forceinline__ float sigmoidf_(float x) {
    return 1.f / (1.f + __expf(-x));
}
__device__ __forceinline__ float tanhf_(float x) {
    const float xc = fminf(fmaxf(x, -10.f), 10.f);
    const float t = __expf(2.f * xc);
    return (t - 1.f) / (t + 1.f);
}

__device__ __forceinline__ ushort f2bf(float f) {
    union { float f; unsigned u; } v; v.f = f;
    const unsigned r = (v.u + 0x7FFFu + ((v.u >> 16) & 1u)) >> 16;
    return (ushort)r;
}
__device__ __forceinline__ float bf2f(ushort u) {
    union { unsigned u; float f; } v; v.u = ((unsigned)u) << 16; return v.f;
}

__device__ __forceinline__ void gload16(const void* g, void* l) {
    __builtin_amdgcn_global_load_lds(
        (const __attribute__((address_space(1))) void*)g,
        (__attribute__((address_space(3))) void*)l, 16, 0, 0);
}

// ---------------------------------------------------------------------------
// Kernel 0: convert weights to bf16: Wih_f|Whh_f|Wih_b|Whh_b|Wb|Kemb
// ---------------------------------------------------------------------------
__global__ __launch_bounds__(256) void wcvt_kernel(
    const float* __restrict__ w0, const float* __restrict__ w1,
    const float* __restrict__ w2, const float* __restrict__ w3,
    const float* __restrict__ w4, const float* __restrict__ w5,
    ushort* __restrict__ dst)
{
    const int idx = (blockIdx.x * 256 + threadIdx.x) * 4;
    const float* src; int local;
    if      (idx < S0_)                  { src = w0; local = idx; }
    else if (idx < S0_ + S1_)            { src = w1; local = idx - S0_; }
    else if (idx < 2*S0_ + S1_)          { src = w2; local = idx - S0_ - S1_; }
    else if (idx < 2*S0_ + 2*S1_)        { src = w3; local = idx - 2*S0_ - S1_; }
    else if (idx < 2*S0_ + 2*S1_ + WB_)  { src = w4; local = idx - 2*S0_ - 2*S1_; }
    else                                 { src = w5; local = idx - 2*S0_ - 2*S1_ - WB_; }
    const float4 v = *(const float4*)(src + local);
    ushort4 o; o.x = f2bf(v.x); o.y = f2bf(v.y); o.z = f2bf(v.z); o.w = f2bf(v.w);
    *(ushort4*)(dst + idx) = o;
}

// ---------------------------------------------------------------------------
// Kernel 1: masked mean pooling -> x1 (tab), x2 (col) in bf16
// ---------------------------------------------------------------------------
__global__ __launch_bounds__(256) void meanpool_kernel(
    const float* __restrict__ feat,
    const int* __restrict__ col_idx, const int* __restrict__ col_mask,
    const int* __restrict__ tab_idx, const int* __restrict__ tab_mask,
    ushort* __restrict__ x1, ushort* __restrict__ x2)
{
    const int u = blockIdx.x;
    const int t = blockIdx.y;
    const int tid = threadIdx.x;

    int ci[MC_], cm[MC_], ti[MT_], tm[MT_];
    float cc = 0.f, tc = 0.f;
#pragma unroll
    for (int m = 0; m < MC_; ++m) { ci[m] = col_idx[u*MC_+m]; cm[m] = col_mask[u*MC_+m]; cc += (float)cm[m]; }
#pragma unroll
    for (int m = 0; m < MT_; ++m) { ti[m] = tab_idx[u*MT_+m]; tm[m] = tab_mask[u*MT_+m]; tc += (float)tm[m]; }
    const float rc = 1.f / fmaxf(cc, 1.f);
    const float rt = 1.f / fmaxf(tc, 1.f);

    const float* fb = feat + (size_t)t * DB2_ * H_;
    const int h = tid * 2;

    float acx = 0.f, acy = 0.f, atx = 0.f, aty = 0.f;
#pragma unroll
    for (int m = 0; m < MC_; ++m) if (cm[m]) {
        const float2 v = *(const float2*)(fb + (size_t)ci[m]*H_ + h);
        acx += v.x; acy += v.y;
    }
#pragma unroll
    for (int m = 0; m < MT_; ++m) if (tm[m]) {
        const float2 v = *(const float2*)(fb + (size_t)ti[m]*H_ + h);
        atx += v.x; aty += v.y;
    }
    const size_t o = ((size_t)(t*U_ + u))*H_ + h;
    ushort2 c2; c2.x = f2bf(acx*rc); c2.y = f2bf(acy*rc);
    ushort2 t2; t2.x = f2bf(atx*rt); t2.y = f2bf(aty*rt);
    *(ushort2*)(x2 + o) = c2;
    *(ushort2*)(x1 + o) = t2;
}

// ---------------------------------------------------------------------------
// GRU cells via MFMA. BM=64, 4 waves of 32x32x3gates, swizzled LDS.
// T3-minimum double-buffer: stage next K-tile into buf^1, counted
// s_waitcnt vmcnt(8) + RAW s_barrier (no full drain), compute buf, barrier.
// LDS 64 KB -> 2 blocks/CU (launch_bounds(256,2)).
// ---------------------------------------------------------------------------
__device__ __forceinline__ void stage8(
    ushort* asb, ushort* bsb, int wid,
    const ushort* a0, const ushort* a1,
    const ushort* b0, const ushort* b1, const ushort* b2,
    const ushort* b3, const ushort* b4, const ushort* b5)
{
    gload16(a0, asb + (size_t)wid*512);
    gload16(a1, asb + (size_t)(wid+4)*512);
    gload16(b0, bsb + (size_t)(wid     )*512);
    gload16(b1, bsb + (size_t)(wid +  4)*512);
    gload16(b2, bsb + (size_t)(wid +  8)*512);
    gload16(b3, bsb + (size_t)(wid + 12)*512);
    gload16(b4, bsb + (size_t)(wid + 16)*512);
    gload16(b5, bsb + (size_t)(wid + 20)*512);
}

template<int GN>
__device__ __forceinline__ void compute_tile64(
    f32x4 (&acc)[4][2][2],
    const ushort (&As)[BM][BK], const ushort (&Bs)[192][BK],
    int lane, int wm, int wn)
{
#pragma unroll
    for (int s = 0; s < 2; ++s) {
        const int colr = (((s*4 + (lane>>4)) ^ (lane & 7)) * 8);  // swizzled read col
        bf16x8 af[2];
#pragma unroll
        for (int fm = 0; fm < 2; ++fm)
            af[fm] = *(const bf16x8*)&As[wm*32 + fm*16 + (lane&15)][colr];
#pragma unroll
        for (int g = 0; g < 3; ++g) {
            const int gi = (g == 2) ? GN : g;
#pragma unroll
            for (int fn = 0; fn < 2; ++fn) {
                const bf16x8 bv = *(const bf16x8*)&Bs[g*64 + wn*32 + fn*16 + (lane&15)][colr];
#pragma unroll
                for (int fm = 0; fm < 2; ++fm)
                    acc[gi][fm][fn] = __builtin_amdgcn_mfma_f32_16x16x32_bf16(
                        af[fm], bv, acc[gi][fm][fn], 0, 0, 0);
            }
        }
    }
}

template<bool HAS_H>
__global__ __launch_bounds__(256, 2) void gru2_kernel(
    const ushort* __restrict__ X0, const ushort* __restrict__ X1,
    const ushort* __restrict__ Hb0, const ushort* __restrict__ Hb1,
    const ushort* __restrict__ Wih0, const ushort* __restrict__ Wih1,
    const ushort* __restrict__ Whh0, const ushort* __restrict__ Whh1,
    const float* __restrict__ bih0, const float* __restrict__ bih1,
    const float* __restrict__ bhh0, const float* __restrict__ bhh1,
    ushort* __restrict__ HoutB0, ushort* __restrict__ HoutB1,
    ushort* __restrict__ emb0, ushort* __restrict__ emb1)
{
    __shared__ __align__(16) ushort As[2][BM][BK];    // 16 KB
    __shared__ __align__(16) ushort Bs[2][192][BK];   // 48 KB

    const int sel = blockIdx.z;
    const ushort* Xb   = sel ? X1 : X0;
    const ushort* Hb   = sel ? Hb1 : Hb0;
    const ushort* Wihb = sel ? Wih1 : Wih0;
    const ushort* Whhb = sel ? Whh1 : Whh0;
    const float*  bih  = sel ? bih1 : bih0;
    const float*  bhh  = sel ? bhh1 : bhh0;
    ushort* Hout_b = sel ? HoutB1 : HoutB0;
    ushort* emb_b  = sel ? emb1 : emb0;

    const int tid = threadIdx.x;
    const int lane = tid & 63, wid = tid >> 6;
    const int wm = wid >> 1, wn = wid & 1;

    // XCD remap: flat = ((ib/8)*4 + jb)*8 + ib%8  (bijective on [0,1024))
    const int flat = blockIdx.x;
    const int i8   = flat & 7;
    const int rest = flat >> 3;
    const int jb   = rest & 3;
    const int ib   = (rest >> 2) * 8 + i8;
    const int i0 = ib * BM;
    const int j0 = jb * BNG;

    const int csw  = (((lane & 7) ^ (lane >> 3)) * 8);
    const int rsub = lane >> 3;

    // phase-1 global pointers (advanced by BK per staged step)
    const ushort* xa0 = Xb + (size_t)(i0 + wid*8     + rsub)*H_ + csw;
    const ushort* xa1 = Xb + (size_t)(i0 + (wid+4)*8 + rsub)*H_ + csw;
    const ushort* xb[6];
#pragma unroll
    for (int s = 0; s < 6; ++s) {
        const int rowB = (wid + 4*s)*8 + rsub;
        xb[s] = Wihb + (size_t)((rowB>>6)*Hh_ + j0 + (rowB&63))*H_ + csw;
    }
    // phase-2 global pointers
    const ushort* ha0 = nullptr; const ushort* ha1 = nullptr;
    const ushort* hb[6] = {};
    if (HAS_H) {
        ha0 = Hb + (size_t)(i0 + wid*8     + rsub)*Hh_ + csw;
        ha1 = Hb + (size_t)(i0 + (wid+4)*8 + rsub)*Hh_ + csw;
#pragma unroll
        for (int s = 0; s < 6; ++s) {
            const int rowB = (wid + 4*s)*8 + rsub;
            hb[s] = Whhb + (size_t)((rowB>>6)*Hh_ + j0 + (rowB&63))*Hh_ + csw;
        }
    }

    f32x4 acc[4][2][2] = {};   // [r,z,n_ih | n_hh][fm][fn]

    const int NK1 = H_ / BK;   // 8
    const int NK2 = Hh_ / BK;  // 4
    int cur = 0;

    // prologue: stage k0=0 into buf0
    stage8(&As[0][0][0], &Bs[0][0][0], wid, xa0, xa1,
           xb[0], xb[1], xb[2], xb[3], xb[4], xb[5]);

    // ---- phase 1: X @ Wih^T ----
    for (int k = 1; k <= NK1; ++k) {
        if (k < NK1) {
            xa0 += BK; xa1 += BK;
#pragma unroll
            for (int s = 0; s < 6; ++s) xb[s] += BK;
            stage8(&As[cur^1][0][0], &Bs[cur^1][0][0], wid, xa0, xa1,
                   xb[0], xb[1], xb[2], xb[3], xb[4], xb[5]);
            asm volatile("s_waitcnt vmcnt(8)" ::: "memory");
        } else if (HAS_H) {
            stage8(&As[cur^1][0][0], &Bs[cur^1][0][0], wid, ha0, ha1,
                   hb[0], hb[1], hb[2], hb[3], hb[4], hb[5]);
            asm volatile("s_waitcnt vmcnt(8)" ::: "memory");
        } else {
            asm volatile("s_waitcnt vmcnt(0)" ::: "memory");
        }
        __builtin_amdgcn_s_barrier();          // raw: no auto vmcnt(0) drain
        __builtin_amdgcn_sched_barrier(0);     // keep ds_reads below the barrier
        compute_tile64<2>(acc, As[cur], Bs[cur], lane, wm, wn);
        __builtin_amdgcn_s_barrier();          // all waves done reading buf[cur]
        cur ^= 1;
    }
    // ---- phase 2: H @ Whh^T ----
    if (HAS_H) {
        for (int k = 1; k <= NK2; ++k) {
            if (k < NK2) {
                ha0 += BK; ha1 += BK;
#pragma unroll
                for (int s = 0; s < 6; ++s) hb[s] += BK;
                stage8(&As[cur^1][0][0], &Bs[cur^1][0][0], wid, ha0, ha1,
                       hb[0], hb[1], hb[2], hb[3], hb[4], hb[5]);
                asm volatile("s_waitcnt vmcnt(8)" ::: "memory");
            } else {
                asm volatile("s_waitcnt vmcnt(0)" ::: "memory");
            }
            __builtin_amdgcn_s_barrier();
            __builtin_amdgcn_sched_barrier(0);
            compute_tile64<3>(acc, As[cur], Bs[cur], lane, wm, wn);
            __builtin_amdgcn_s_barrier();
            cur ^= 1;
        }
    }

#pragma unroll
    for (int fn = 0; fn < 2; ++fn) {
        const int j = j0 + wn*32 + fn*16 + (lane & 15);
        const float bri = bih[j],       brh = bhh[j];
        const float bzi = bih[Hh_ + j], bzh = bhh[Hh_ + j];
        const float bni = bih[2*Hh_+j], bnh = bhh[2*Hh_ + j];
#pragma unroll
        for (int fm = 0; fm < 2; ++fm) {
#pragma unroll
            for (int r = 0; r < 4; ++r) {
                const int i = i0 + wm*32 + fm*16 + (lane >> 4)*4 + r;
                const float xr = acc[0][fm][fn][r] + bri + brh;
                const float xz = acc[1][fm][fn][r] + bzi + bzh;
                const float xn = acc[2][fm][fn][r] + bni;
                float hn = bnh, hprev = 0.f;
                if (HAS_H) { hn += acc[3][fm][fn][r]; hprev = bf2f(Hb[(size_t)i*Hh_ + j]); }
                const float rg = sigmoidf_(xr);
                const float zg = sigmoidf_(xz);
                const float ng = tanhf_(xn + rg * hn);
                const float hp = (1.f - zg) * ng + zg * hprev;
                if (HAS_H) {
                    emb_b[(size_t)i*H_ + j] = f2bf(0.5f * (hprev + hp));
                } else {
                    Hout_b[(size_t)i*Hh_ + j] = f2bf(hp);
                }
            }
        }
    }
}

// ---------------------------------------------------------------------------
// block reductions
// ---------------------------------------------------------------------------
template<int NT>
__device__ __forceinline__ float block_reduce_max(float v, float* red) {
#pragma unroll
    for (int o = 32; o > 0; o >>= 1) v = fmaxf(v, __shfl_down(v, o));
    const int wid = threadIdx.x >> 6;
    if ((threadIdx.x & 63) == 0) red[wid] = v;
    __syncthreads();
    if (threadIdx.x == 0) {
        float m = red[0];
#pragma unroll
        for (int i = 1; i < NT/64; ++i) m = fmaxf(m, red[i]);
        red[0] = m;
    }
    __syncthreads();
    const float r = red[0];
    __syncthreads();
    return r;
}

template<int NT>
__device__ __forceinline__ float block_reduce_sum(float v, float* red) {
#pragma unroll
    for (int o = 32; o > 0; o >>= 1) v += __shfl_down(v, o);
    const int wid = threadIdx.x >> 6;
    if ((threadIdx.x & 63) == 0) red[wid] = v;
    __syncthreads();
    if (threadIdx.x == 0) {
        float m = red[0];
#pragma unroll
        for (int i = 1; i < NT/64; ++i) m += red[i];
        red[0] = m;
    }
    __syncthreads();
    const float r = red[0];
    __syncthreads();
    return r;
}

// ---------------------------------------------------------------------------
// attention, split for parallelism.
// A: logits.  grid (16, T), 256 threads: 64 u/block, 4 threads per u.
// ---------------------------------------------------------------------------
__global__ __launch_bounds__(256) void attn_logits_kernel(
    const ushort* __restrict__ db, const float* __restrict__ key,
    const int* __restrict__ attn_mask, float* __restrict__ alog)
{
    const int t = blockIdx.y;
    const int tid = threadIdx.x;
    const int u = blockIdx.x*64 + (tid >> 2);
    const int kq = (tid & 3) * 128;

    const bf16x8* r8 = (const bf16x8*)(db + ((size_t)t*U_ + u)*H_ + kq);
    const float* kp = key + t*H_ + kq;
    float s = 0.f;
#pragma unroll
    for (int k8 = 0; k8 < 16; ++k8) {
        const bf16x8 v = r8[k8];
#pragma unroll
        for (int j = 0; j < 8; ++j)
            s = fmaf(kp[k8*8 + j], bf2f((ushort)v[j]), s);
    }
    s += __shfl_xor(s, 1);
    s += __shfl_xor(s, 2);
    if ((tid & 3) == 0)
        alog[t*U_ + u] = attn_mask[t*U_ + u] ? s : -1e9f;
}

// B: softmax -> weights. grid T, 512 threads.
__global__ __launch_bounds__(512) void attn_softmax_kernel(
    const float* __restrict__ alog, float* __restrict__ aw)
{
    __shared__ float red[8];
    const int t = blockIdx.x, tid = threadIdx.x;
    const float v0 = alog[t*U_ + tid], v1 = alog[t*U_ + tid + 512];
    const float m = block_reduce_max<512>(fmaxf(v0, v1), red);
    const float e0 = __expf(v0 - m), e1 = __expf(v1 - m);
    const float s = block_reduce_sum<512>(e0 + e1, red);
    const float inv = 1.f / s;
    aw[t*U_ + tid] = e0 * inv;
    aw[t*U_ + tid + 512] = e1 * inv;
}

// C: weighted sum partials. grid (8, T), 512 threads = 8 u-slices x 64 h-octets.
__global__ __launch_bounds__(512) void attn_wsum_kernel(
    const ushort* __restrict__ db, const float* __restrict__ aw,
    float* __restrict__ part)
{
    __shared__ float sred[8][64][8];   // 16 KB
    const int t = blockIdx.y, u0 = blockIdx.x * 128;
    const int usub = threadIdx.x >> 6;   // 0..7
    const int h8   = threadIdx.x & 63;   // 0..63

    float a[8] = {};
    for (int uu = 0; uu < 16; ++uu) {
        const int u = u0 + usub*16 + uu;
        const float w = aw[t*U_ + u];
        const bf16x8 v = *(const bf16x8*)(db + ((size_t)t*U_ + u)*H_ + h8*8);
#pragma unroll
        for (int j = 0; j < 8; ++j) a[j] = fmaf(w, bf2f((ushort)v[j]), a[j]);
    }
#pragma unroll
    for (int j = 0; j < 8; ++j) sred[usub][h8][j] = a[j];
    __syncthreads();

    const int h8r = threadIdx.x >> 3;    // 0..63
    const int cr  = threadIdx.x & 7;     // 0..7
    float s = 0.f;
#pragma unroll
    for (int us = 0; us < 8; ++us) s += sred[us][h8r][cr];
    part[((size_t)blockIdx.x*T_ + t)*H_ + h8r*8 + cr] = s;
}

// ---------------------------------------------------------------------------
// feature = finf + sum(part) -> bf16
// ---------------------------------------------------------------------------
__global__ __launch_bounds__(256) void featcvt_kernel(
    const float* __restrict__ finf, const float* __restrict__ part,
    ushort* __restrict__ featb)
{
    const int row = blockIdx.x;       // t*64+l
    const int t = row >> 6;
    const int h = threadIdx.x * 2;
    const float2 v = *(const float2*)(finf + (size_t)row*H_ + h);
    float ax = 0.f, ay = 0.f;
#pragma unroll
    for (int p = 0; p < 8; ++p) {
        const float2 a = *(const float2*)(part + ((size_t)p*T_ + t)*H_ + h);
        ax += a.x; ay += a.y;
    }
    ushort2 o; o.x = f2bf(v.x + ax); o.y = f2bf(v.y + ay);
    *(ushort2*)(featb + (size_t)row*H_ + h) = o;
}

// ---------------------------------------------------------------------------
// ff = tanh(featb @ Wb^T + bb) -> bf16.  M=1024, N=512, K=512. Swizzled LDS.
// ---------------------------------------------------------------------------
__global__ __launch_bounds__(256) void ffgemm_kernel(
    const ushort* __restrict__ featb, const ushort* __restrict__ Wbb,
    const float* __restrict__ bb, ushort* __restrict__ ffb)
{
    __shared__ __align__(16) ushort As[128][BK];  // 16 KB
    __shared__ __align__(16) ushort Bs[64][BK];   // 8 KB

    const int tid = threadIdx.x;
    const int lane = tid & 63, wid = tid >> 6;
    const int wm = wid >> 1, wn = wid & 1;
    const int i0 = blockIdx.y * 128;
    const int j0 = blockIdx.x * 64;
    const int csw  = (((lane & 7) ^ (lane >> 3)) * 8);
    const int rsub = lane >> 3;

    f32x4 acc[4][2] = {};

    for (int k0 = 0; k0 < H_; k0 += BK) {
#pragma unroll
        for (int cc = wid; cc < 24; cc += 4) {
            if (cc < 16) {
                const ushort* g = featb + (size_t)(i0 + cc*8 + rsub)*H_ + k0 + csw;
                gload16(g, &As[0][0] + cc*512);
            } else {
                const int c = cc - 16;
                const ushort* g = Wbb + (size_t)(j0 + c*8 + rsub)*H_ + k0 + csw;
                gload16(g, &Bs[0][0] + c*512);
            }
        }
        __syncthreads();
#pragma unroll
        for (int s = 0; s < 2; ++s) {
            const int colr = (((s*4 + (lane>>4)) ^ (lane & 7)) * 8);
            bf16x8 af[4];
#pragma unroll
            for (int fm = 0; fm < 4; ++fm)
                af[fm] = *(const bf16x8*)&As[wm*64 + fm*16 + (lane&15)][colr];
#pragma unroll
            for (int fn = 0; fn < 2; ++fn) {
                const bf16x8 bv = *(const bf16x8*)&Bs[wn*32 + fn*16 + (lane&15)][colr];
#pragma unroll
                for (int fm = 0; fm < 4; ++fm)
                    acc[fm][fn] = __builtin_amdgcn_mfma_f32_16x16x32_bf16(
                        af[fm], bv, acc[fm][fn], 0, 0, 0);
            }
        }
        __syncthreads();
    }

#pragma unroll
    for (int fn = 0; fn < 2; ++fn) {
        const int j = j0 + wn*32 + fn*16 + (lane & 15);
        const float b = bb[j];
#pragma unroll
        for (int fm = 0; fm < 4; ++fm)
#pragma unroll
            for (int r = 0; r < 4; ++r) {
                const int i = i0 + wm*64 + fm*16 + (lane >> 4)*4 + r;
                ffb[(size_t)i*H_ + j] = f2bf(tanhf_(acc[fm][fn][r] + b));
            }
    }
}

// ---------------------------------------------------------------------------
// logits[t*64+l, n] = ff[t*64+l,:] . V[n,:].  Swizzled LDS.
// ---------------------------------------------------------------------------
__global__ __launch_bounds__(256) void logits_kernel(
    const ushort* __restrict__ ffb, const ushort* __restrict__ dbb,
    const ushort* __restrict__ Kembb, float* __restrict__ logits)
{
    __shared__ __align__(16) ushort As[64][BK];   // 8 KB
    __shared__ __align__(16) ushort Bs[64][BK];   // 8 KB

    const int tid = threadIdx.x;
    const int lane = tid & 63, wid = tid >> 6;
    const int t = blockIdx.y;
    const int bx = blockIdx.x;
    const bool kw = (bx == 16);
    const int csw  = (((lane & 7) ^ (lane >> 3)) * 8);
    const int rsub = lane >> 3;

    f32x4 acc[4] = {};

    for (int k0 = 0; k0 < H_; k0 += BK) {
#pragma unroll
        for (int cc = wid; cc < 16; cc += 4) {
            if (cc < 8) {
                const ushort* g = ffb + (size_t)(t*64 + cc*8 + rsub)*H_ + k0 + csw;
                gload16(g, &As[0][0] + cc*512);
            } else {
                const int rloc = (cc-8)*8 + rsub;
                const ushort* g = kw ? (Kembb + (size_t)rloc*H_ + k0 + csw)
                                     : (dbb + (size_t)(t*U_ + bx*64 + rloc)*H_ + k0 + csw);
                gload16(g, &Bs[0][0] + (cc-8)*512);
            }
        }
        __syncthreads();
#pragma unroll
        for (int s = 0; s < 2; ++s) {
            const int colr = (((s*4 + (lane>>4)) ^ (lane & 7)) * 8);
            const bf16x8 af = *(const bf16x8*)&As[wid*16 + (lane&15)][colr];
#pragma unroll
            for (int fn = 0; fn < 4; ++fn) {
                const bf16x8 bv = *(const bf16x8*)&Bs[fn*16 + (lane&15)][colr];
                acc[fn] = __builtin_amdgcn_mfma_f32_16x16x32_bf16(af, bv, acc[fn], 0, 0, 0);
            }
        }
        __syncthreads();
    }

    const int ncols = U_ + K_;
#pragma unroll
    for (int fn = 0; fn < 4; ++fn) {
        const int jg = (kw ? U_ : bx*64) + fn*16 + (lane & 15);
#pragma unroll
        for (int r = 0; r < 4; ++r) {
            const int i = t*64 + wid*16 + (lane >> 4)*4 + r;
            logits[(size_t)i*ncols + jg] = acc[fn][r];
        }
    }
}

// ---------------------------------------------------------------------------
// per-row log_softmax over 1088 logits
// ---------------------------------------------------------------------------
__global__ __launch_bounds__(256) void lsm_kernel(
    const float* __restrict__ logits, float* __restrict__ out)
{
    __shared__ float sl[U_ + K_];
    __shared__ float red[4];
    const int row = blockIdx.x;
    const int tid = threadIdx.x;
    const int ncols = U_ + K_;

    float m = -3.4e38f;
    for (int idx = tid; idx < ncols; idx += 256) {
        const float v = logits[(size_t)row*ncols + idx];
        sl[idx] = v;
        m = fmaxf(m, v);
    }
    __syncthreads();
    m = block_reduce_max<256>(m, red);

    float s = 0.f;
    for (int idx = tid; idx < ncols; idx += 256) s += __expf(sl[idx] - m);
    s = block_reduce_sum<256>(s, red);
    const float lse = m + __logf(s);

    for (int idx = tid; idx < ncols; idx += 256)
        out[(size_t)row*ncols + idx] = sl[idx] - lse;
}

// ---------------------------------------------------------------------------
extern "C" void kernel_launch(void* const* d_in, const int* in_sizes, int n_in,
                              void* d_out, int out_size, void* d_ws, size_t ws_size,
                              hipStream_t stream)
{
    const float* feat  = (const float*)d_in[0];
    const float* key   = (const float*)d_in[1];
    const float* finf  = (const float*)d_in[2];
    const float* Wih_f = (const float*)d_in[3];
    const float* Whh_f = (const float*)d_in[4];
    const float* bih_f = (const float*)d_in[5];
    const float* bhh_f = (const float*)d_in[6];
    const float* Wih_b = (const float*)d_in[7];
    const float* Whh_b = (const float*)d_in[8];
    const float* bih_b = (const float*)d_in[9];
    const float* bhh_b = (const float*)d_in[10];
    const float* Wb    = (const float*)d_in[11];
    const float* bb    = (const float*)d_in[12];
    const float* Kemb  = (const float*)d_in[13];
    const int* col_idx  = (const int*)d_in[14];
    const int* col_mask = (const int*)d_in[15];
    const int* tab_idx  = (const int*)d_in[16];
    const int* tab_mask = (const int*)d_in[17];
    const int* attn_mask= (const int*)d_in[18];
    float* out = (float*)d_out;

    char* p = (char*)d_ws;
    ushort* wbf  = (ushort*)p;  p += (size_t)(2*(S0_+S1_) + WB_ + KE_)*2;  // 2.95 MB
    ushort* x1b  = (ushort*)p;  p += (size_t)M_*H_*2;                      // 16.8 MB
    ushort* x2b  = (ushort*)p;  p += (size_t)M_*H_*2;
    ushort* f1b  = (ushort*)p;  p += (size_t)M_*Hh_*2;
    ushort* b1b  = (ushort*)p;  p += (size_t)M_*Hh_*2;
    ushort* dbb  = (ushort*)p;  p += (size_t)M_*H_*2;                      // 16.8 MB
    float*  alog = (float*)p;   p += (size_t)T_*U_*4;
    float*  aw   = (float*)p;   p += (size_t)T_*U_*4;
    float*  part = (float*)p;   p += (size_t)8*T_*H_*4;
    ushort* featb= (ushort*)p;  p += (size_t)T_*L_*H_*2;
    ushort* ffb  = (ushort*)p;  p += (size_t)T_*L_*H_*2;
    float*  lg   = (float*)p;   p += (size_t)T_*L_*(U_+K_)*4;              // 4.45 MB

    const ushort* Wihf_b = wbf;
    const ushort* Whhf_b = wbf + S0_;
    const ushort* Wihb_b = wbf + S0_ + S1_;
    const ushort* Whhb_b = wbf + 2*S0_ + S1_;
    const ushort* Wbb    = wbf + 2*(S0_ + S1_);
    const ushort* Kembb  = wbf + 2*(S0_ + S1_) + WB_;

    wcvt_kernel<<<(2*(S0_+S1_) + WB_ + KE_)/1024, 256, 0, stream>>>(
        Wih_f, Whh_f, Wih_b, Whh_b, Wb, Kemb, wbf);

    meanpool_kernel<<<dim3(U_, T_), 256, 0, stream>>>(
        feat, col_idx, col_mask, tab_idx, tab_mask, x1b, x2b);

    dim3 gg((M_/BM)*(Hh_/BNG), 1, 2);   // (1024, 1, 2), XCD-remapped in-kernel
    gru2_kernel<false><<<gg, 256, 0, stream>>>(
        x1b, x2b, nullptr, nullptr,
        Wihf_b, Wihb_b, Whhf_b, Whhb_b, bih_f, bih_b, bhh_f, bhh_b,
        f1b, b1b, nullptr, nullptr);
    gru2_kernel<true><<<gg, 256, 0, stream>>>(
        x2b, x1b, f1b, b1b,
        Wihf_b, Wihb_b, Whhf_b, Whhb_b, bih_f, bih_b, bhh_f, bhh_b,
        nullptr, nullptr, dbb, dbb + Hh_);

    attn_logits_kernel<<<dim3(16, T_), 256, 0, stream>>>(dbb, key, attn_mask, alog);
    attn_softmax_kernel<<<T_, 512, 0, stream>>>(alog, aw);
    attn_wsum_kernel<<<dim3(8, T_), 512, 0, stream>>>(dbb, aw, part);
    featcvt_kernel<<<T_*L_, 256, 0, stream>>>(finf, part, featb);
    ffgemm_kernel<<<dim3(H_/64, (T_*L_)/128), 256, 0, stream>>>(featb, Wbb, bb, ffb);
    logits_kernel<<<dim3(17, T_), 256, 0, stream>>>(ffb, dbb, Kembb, lg);
    lsm_kernel<<<T_*L_, 256, 0, stream>>>(lg, out);
}

// Round 12
// 254.319 us; speedup vs baseline: 1.0153x; 1.0153x over previous
//
#include <hip/hip_runtime.h>
#include <math.h>

#define T_  16
#define DB2_ 512
#define H_  512
#define Hh_ 256
#define U_  1024
#define MC_ 8
#define MT_ 4
#define L_  64
#define K_  64
#define M_  (T_*U_)   // 16384

#define BM 64
#define BNG 64
#define BK 64
#define S0_ (768*512)
#define S1_ (768*256)
#define WB_ (512*512)
#define KE_ (64*512)

typedef __attribute__((ext_vector_type(8))) short bf16x8;
typedef __attribute__((ext_vector_type(4))) float f32x4;

__device__ __forceinline__ float sigmoidf_(float x) {
    return 1.f / (1.f + __expf(-x));
}
__device__ __forceinline__ float tanhf_(float x) {
    const float xc = fminf(fmaxf(x, -10.f), 10.f);
    const float t = __expf(2.f * xc);
    return (t - 1.f) / (t + 1.f);
}

__device__ __forceinline__ ushort f2bf(float f) {
    union { float f; unsigned u; } v; v.f = f;
    const unsigned r = (v.u + 0x7FFFu + ((v.u >> 16) & 1u)) >> 16;
    return (ushort)r;
}
__device__ __forceinline__ float bf2f(ushort u) {
    union { unsigned u; float f; } v; v.u = ((unsigned)u) << 16; return v.f;
}

__device__ __forceinline__ void gload16(const void* g, void* l) {
    __builtin_amdgcn_global_load_lds(
        (const __attribute__((address_space(1))) void*)g,
        (__attribute__((address_space(3))) void*)l, 16, 0, 0);
}

// ---------------------------------------------------------------------------
// Kernel 0: convert weights to bf16: Wih_f|Whh_f|Wih_b|Whh_b|Wb|Kemb
// ---------------------------------------------------------------------------
__global__ __launch_bounds__(256) void wcvt_kernel(
    const float* __restrict__ w0, const float* __restrict__ w1,
    const float* __restrict__ w2, const float* __restrict__ w3,
    const float* __restrict__ w4, const float* __restrict__ w5,
    ushort* __restrict__ dst)
{
    const int idx = (blockIdx.x * 256 + threadIdx.x) * 4;
    const float* src; int local;
    if      (idx < S0_)                  { src = w0; local = idx; }
    else if (idx < S0_ + S1_)            { src = w1; local = idx - S0_; }
    else if (idx < 2*S0_ + S1_)          { src = w2; local = idx - S0_ - S1_; }
    else if (idx < 2*S0_ + 2*S1_)        { src = w3; local = idx - 2*S0_ - S1_; }
    else if (idx < 2*S0_ + 2*S1_ + WB_)  { src = w4; local = idx - 2*S0_ - 2*S1_; }
    else                                 { src = w5; local = idx - 2*S0_ - 2*S1_ - WB_; }
    const float4 v = *(const float4*)(src + local);
    ushort4 o; o.x = f2bf(v.x); o.y = f2bf(v.y); o.z = f2bf(v.z); o.w = f2bf(v.w);
    *(ushort4*)(dst + idx) = o;
}

// ---------------------------------------------------------------------------
// Kernel 1: masked mean pooling -> x1 (tab), x2 (col) in bf16.
// float4 loads, 2 u per block (128 threads per u).
// ---------------------------------------------------------------------------
__global__ __launch_bounds__(256) void meanpool_kernel(
    const float* __restrict__ feat,
    const int* __restrict__ col_idx, const int* __restrict__ col_mask,
    const int* __restrict__ tab_idx, const int* __restrict__ tab_mask,
    ushort* __restrict__ x1, ushort* __restrict__ x2)
{
    const int tid = threadIdx.x;
    const int u = blockIdx.x*2 + (tid >> 7);
    const int t = blockIdx.y;
    const int h = (tid & 127) * 4;

    int ci[MC_], cm[MC_], ti[MT_], tm[MT_];
    float cc = 0.f, tc = 0.f;
#pragma unroll
    for (int m = 0; m < MC_; ++m) { ci[m] = col_idx[u*MC_+m]; cm[m] = col_mask[u*MC_+m]; cc += (float)cm[m]; }
#pragma unroll
    for (int m = 0; m < MT_; ++m) { ti[m] = tab_idx[u*MT_+m]; tm[m] = tab_mask[u*MT_+m]; tc += (float)tm[m]; }
    const float rc = 1.f / fmaxf(cc, 1.f);
    const float rt = 1.f / fmaxf(tc, 1.f);

    const float* fb = feat + (size_t)t * DB2_ * H_;

    float4 ac = make_float4(0.f,0.f,0.f,0.f), at = make_float4(0.f,0.f,0.f,0.f);
#pragma unroll
    for (int m = 0; m < MC_; ++m) if (cm[m]) {
        const float4 v = *(const float4*)(fb + (size_t)ci[m]*H_ + h);
        ac.x += v.x; ac.y += v.y; ac.z += v.z; ac.w += v.w;
    }
#pragma unroll
    for (int m = 0; m < MT_; ++m) if (tm[m]) {
        const float4 v = *(const float4*)(fb + (size_t)ti[m]*H_ + h);
        at.x += v.x; at.y += v.y; at.z += v.z; at.w += v.w;
    }
    const size_t o = ((size_t)(t*U_ + u))*H_ + h;
    ushort4 c4; c4.x = f2bf(ac.x*rc); c4.y = f2bf(ac.y*rc); c4.z = f2bf(ac.z*rc); c4.w = f2bf(ac.w*rc);
    ushort4 t4; t4.x = f2bf(at.x*rt); t4.y = f2bf(at.y*rt); t4.z = f2bf(at.z*rt); t4.w = f2bf(at.w*rt);
    *(ushort4*)(x2 + o) = c4;
    *(ushort4*)(x1 + o) = t4;
}

// ---------------------------------------------------------------------------
// GRU cells via MFMA, swizzled LDS.  BM=64, 4 waves of 32x32x3gates.
// R10 structure (measured best): single buffer, hoisted loop-carried pointers,
// __syncthreads; unified-regfile cap (64 VGPR + 64 AGPR acc) => 4 waves/SIMD.
// blockIdx.x XCD-remapped.
// ---------------------------------------------------------------------------
template<int GN>
__device__ __forceinline__ void compute_tile64(
    f32x4 (&acc)[4][2][2],
    const ushort (&As)[BM][BK], const ushort (&Bs)[192][BK],
    int lane, int wm, int wn)
{
#pragma unroll
    for (int s = 0; s < 2; ++s) {
        const int colr = (((s*4 + (lane>>4)) ^ (lane & 7)) * 8);  // swizzled read col
        bf16x8 af[2];
#pragma unroll
        for (int fm = 0; fm < 2; ++fm)
            af[fm] = *(const bf16x8*)&As[wm*32 + fm*16 + (lane&15)][colr];
#pragma unroll
        for (int g = 0; g < 3; ++g) {
            const int gi = (g == 2) ? GN : g;
#pragma unroll
            for (int fn = 0; fn < 2; ++fn) {
                const bf16x8 bv = *(const bf16x8*)&Bs[g*64 + wn*32 + fn*16 + (lane&15)][colr];
#pragma unroll
                for (int fm = 0; fm < 2; ++fm)
                    acc[gi][fm][fn] = __builtin_amdgcn_mfma_f32_16x16x32_bf16(
                        af[fm], bv, acc[gi][fm][fn], 0, 0, 0);
            }
        }
    }
}

template<bool HAS_H>
__global__ __launch_bounds__(256, 4) void gru2_kernel(
    const ushort* __restrict__ X0, const ushort* __restrict__ X1,
    const ushort* __restrict__ Hb0, const ushort* __restrict__ Hb1,
    const ushort* __restrict__ Wih0, const ushort* __restrict__ Wih1,
    const ushort* __restrict__ Whh0, const ushort* __restrict__ Whh1,
    const float* __restrict__ bih0, const float* __restrict__ bih1,
    const float* __restrict__ bhh0, const float* __restrict__ bhh1,
    ushort* __restrict__ HoutB0, ushort* __restrict__ HoutB1,
    ushort* __restrict__ emb0, ushort* __restrict__ emb1)
{
    __shared__ __align__(16) ushort As[BM][BK];   // 8 KB
    __shared__ __align__(16) ushort Bs[192][BK];  // 24 KB

    const int sel = blockIdx.z;
    const ushort* Xb   = sel ? X1 : X0;
    const ushort* Hb   = sel ? Hb1 : Hb0;
    const ushort* Wihb = sel ? Wih1 : Wih0;
    const ushort* Whhb = sel ? Whh1 : Whh0;
    const float*  bih  = sel ? bih1 : bih0;
    const float*  bhh  = sel ? bhh1 : bhh0;
    ushort* Hout_b = sel ? HoutB1 : HoutB0;
    ushort* emb_b  = sel ? emb1 : emb0;

    const int tid = threadIdx.x;
    const int lane = tid & 63, wid = tid >> 6;
    const int wm = wid >> 1, wn = wid & 1;

    // XCD remap: flat = ((ib/8)*4 + jb)*8 + ib%8  (bijective on [0,1024))
    const int flat = blockIdx.x;
    const int i8   = flat & 7;
    const int rest = flat >> 3;
    const int jb   = rest & 3;
    const int ib   = (rest >> 2) * 8 + i8;
    const int i0 = ib * BM;
    const int j0 = jb * BNG;

    const int csw  = (((lane & 7) ^ (lane >> 3)) * 8);
    const int rsub = lane >> 3;

    // fixed wave-uniform LDS destinations
    ushort* const ldsA0 = &As[0][0] + (size_t)wid*512;
    ushort* const ldsA1 = &As[0][0] + (size_t)(wid+4)*512;
    ushort* ldsB[6];
#pragma unroll
    for (int s = 0; s < 6; ++s) ldsB[s] = &Bs[0][0] + (size_t)(wid + 4*s)*512;

    f32x4 acc[4][2][2] = {};   // [r,z,n_ih | n_hh][fm][fn]

    // ---- phase 1: X @ Wih^T ----
    {
        const ushort* ga0 = Xb + (size_t)(i0 + wid*8     + rsub)*H_ + csw;
        const ushort* ga1 = Xb + (size_t)(i0 + (wid+4)*8 + rsub)*H_ + csw;
        const ushort* gb[6];
#pragma unroll
        for (int s = 0; s < 6; ++s) {
            const int rowB = (wid + 4*s)*8 + rsub;
            gb[s] = Wihb + (size_t)((rowB>>6)*Hh_ + j0 + (rowB&63))*H_ + csw;
        }
        for (int k0 = 0; k0 < H_; k0 += BK) {
            gload16(ga0, ldsA0);
            gload16(ga1, ldsA1);
#pragma unroll
            for (int s = 0; s < 6; ++s) gload16(gb[s], ldsB[s]);
            ga0 += BK; ga1 += BK;
#pragma unroll
            for (int s = 0; s < 6; ++s) gb[s] += BK;
            __syncthreads();
            compute_tile64<2>(acc, As, Bs, lane, wm, wn);
            __syncthreads();
        }
    }
    // ---- phase 2: H @ Whh^T ----
    if (HAS_H) {
        const ushort* ga0 = Hb + (size_t)(i0 + wid*8     + rsub)*Hh_ + csw;
        const ushort* ga1 = Hb + (size_t)(i0 + (wid+4)*8 + rsub)*Hh_ + csw;
        const ushort* gb[6];
#pragma unroll
        for (int s = 0; s < 6; ++s) {
            const int rowB = (wid + 4*s)*8 + rsub;
            gb[s] = Whhb + (size_t)((rowB>>6)*Hh_ + j0 + (rowB&63))*Hh_ + csw;
        }
        for (int k0 = 0; k0 < Hh_; k0 += BK) {
            gload16(ga0, ldsA0);
            gload16(ga1, ldsA1);
#pragma unroll
            for (int s = 0; s < 6; ++s) gload16(gb[s], ldsB[s]);
            ga0 += BK; ga1 += BK;
#pragma unroll
            for (int s = 0; s < 6; ++s) gb[s] += BK;
            __syncthreads();
            compute_tile64<3>(acc, As, Bs, lane, wm, wn);
            __syncthreads();
        }
    }

#pragma unroll
    for (int fn = 0; fn < 2; ++fn) {
        const int j = j0 + wn*32 + fn*16 + (lane & 15);
        const float bri = bih[j],       brh = bhh[j];
        const float bzi = bih[Hh_ + j], bzh = bhh[Hh_ + j];
        const float bni = bih[2*Hh_+j], bnh = bhh[2*Hh_ + j];
#pragma unroll
        for (int fm = 0; fm < 2; ++fm) {
#pragma unroll
            for (int r = 0; r < 4; ++r) {
                const int i = i0 + wm*32 + fm*16 + (lane >> 4)*4 + r;
                const float xr = acc[0][fm][fn][r] + bri + brh;
                const float xz = acc[1][fm][fn][r] + bzi + bzh;
                const float xn = acc[2][fm][fn][r] + bni;
                float hn = bnh, hprev = 0.f;
                if (HAS_H) { hn += acc[3][fm][fn][r]; hprev = bf2f(Hb[(size_t)i*Hh_ + j]); }
                const float rg = sigmoidf_(xr);
                const float zg = sigmoidf_(xz);
                const float ng = tanhf_(xn + rg * hn);
                const float hp = (1.f - zg) * ng + zg * hprev;
                if (HAS_H) {
                    emb_b[(size_t)i*H_ + j] = f2bf(0.5f * (hprev + hp));
                } else {
                    Hout_b[(size_t)i*Hh_ + j] = f2bf(hp);
                }
            }
        }
    }
}

// ---------------------------------------------------------------------------
// block reductions
// ---------------------------------------------------------------------------
template<int NT>
__device__ __forceinline__ float block_reduce_max(float v, float* red) {
#pragma unroll
    for (int o = 32; o > 0; o >>= 1) v = fmaxf(v, __shfl_down(v, o));
    const int wid = threadIdx.x >> 6;
    if ((threadIdx.x & 63) == 0) red[wid] = v;
    __syncthreads();
    if (threadIdx.x == 0) {
        float m = red[0];
#pragma unroll
        for (int i = 1; i < NT/64; ++i) m = fmaxf(m, red[i]);
        red[0] = m;
    }
    __syncthreads();
    const float r = red[0];
    __syncthreads();
    return r;
}

template<int NT>
__device__ __forceinline__ float block_reduce_sum(float v, float* red) {
#pragma unroll
    for (int o = 32; o > 0; o >>= 1) v += __shfl_down(v, o);
    const int wid = threadIdx.x >> 6;
    if ((threadIdx.x & 63) == 0) red[wid] = v;
    __syncthreads();
    if (threadIdx.x == 0) {
        float m = red[0];
#pragma unroll
        for (int i = 1; i < NT/64; ++i) m += red[i];
        red[0] = m;
    }
    __syncthreads();
    const float r = red[0];
    __syncthreads();
    return r;
}

// ---------------------------------------------------------------------------
// attention.
// A: logits.  grid (16, T), 256 threads: 64 u/block, 4 threads per u.
// ---------------------------------------------------------------------------
__global__ __launch_bounds__(256) void attn_logits_kernel(
    const ushort* __restrict__ db, const float* __restrict__ key,
    const int* __restrict__ attn_mask, float* __restrict__ alog)
{
    const int t = blockIdx.y;
    const int tid = threadIdx.x;
    const int u = blockIdx.x*64 + (tid >> 2);
    const int kq = (tid & 3) * 128;

    const bf16x8* r8 = (const bf16x8*)(db + ((size_t)t*U_ + u)*H_ + kq);
    const float* kp = key + t*H_ + kq;
    float s = 0.f;
#pragma unroll
    for (int k8 = 0; k8 < 16; ++k8) {
        const bf16x8 v = r8[k8];
#pragma unroll
        for (int j = 0; j < 8; ++j)
            s = fmaf(kp[k8*8 + j], bf2f((ushort)v[j]), s);
    }
    s += __shfl_xor(s, 1);
    s += __shfl_xor(s, 2);
    if ((tid & 3) == 0)
        alog[t*U_ + u] = attn_mask[t*U_ + u] ? s : -1e9f;
}

// B: weighted sum partials with INLINE softmax (each block recomputes m,s from
// the 4KB alog row — cheaper than a separate 16-block kernel launch).
// grid (8, T), 512 threads = 8 u-slices x 64 h-octets.
__global__ __launch_bounds__(512) void attn_wsum_kernel(
    const ushort* __restrict__ db, const float* __restrict__ alog,
    float* __restrict__ part)
{
    __shared__ float sred[8][64][8];   // 16 KB
    __shared__ float red[8];
    const int t = blockIdx.y, u0 = blockIdx.x * 128;
    const int tid = threadIdx.x;

    // softmax stats over the full row (all 1024 u), 2 values per thread
    const float v0 = alog[t*U_ + tid], v1 = alog[t*U_ + tid + 512];
    const float m = block_reduce_max<512>(fmaxf(v0, v1), red);
    const float ssum = block_reduce_sum<512>(__expf(v0 - m) + __expf(v1 - m), red);
    const float inv = 1.f / ssum;

    const int usub = tid >> 6;   // 0..7
    const int h8   = tid & 63;   // 0..63

    float a[8] = {};
    for (int uu = 0; uu < 16; ++uu) {
        const int u = u0 + usub*16 + uu;
        const float w = __expf(alog[t*U_ + u] - m) * inv;
        const bf16x8 v = *(const bf16x8*)(db + ((size_t)t*U_ + u)*H_ + h8*8);
#pragma unroll
        for (int j = 0; j < 8; ++j) a[j] = fmaf(w, bf2f((ushort)v[j]), a[j]);
    }
#pragma unroll
    for (int j = 0; j < 8; ++j) sred[usub][h8][j] = a[j];
    __syncthreads();

    const int h8r = tid >> 3;    // 0..63
    const int cr  = tid & 7;     // 0..7
    float s = 0.f;
#pragma unroll
    for (int us = 0; us < 8; ++us) s += sred[us][h8r][cr];
    part[((size_t)blockIdx.x*T_ + t)*H_ + h8r*8 + cr] = s;
}

// ---------------------------------------------------------------------------
// feature = finf + sum(part) -> bf16
// ---------------------------------------------------------------------------
__global__ __launch_bounds__(256) void featcvt_kernel(
    const float* __restrict__ finf, const float* __restrict__ part,
    ushort* __restrict__ featb)
{
    const int row = blockIdx.x;       // t*64+l
    const int t = row >> 6;
    const int h = threadIdx.x * 2;
    const float2 v = *(const float2*)(finf + (size_t)row*H_ + h);
    float ax = 0.f, ay = 0.f;
#pragma unroll
    for (int p = 0; p < 8; ++p) {
        const float2 a = *(const float2*)(part + ((size_t)p*T_ + t)*H_ + h);
        ax += a.x; ay += a.y;
    }
    ushort2 o; o.x = f2bf(v.x + ax); o.y = f2bf(v.y + ay);
    *(ushort2*)(featb + (size_t)row*H_ + h) = o;
}

// ---------------------------------------------------------------------------
// ff = tanh(featb @ Wb^T + bb) -> bf16.  M=1024, N=512, K=512. Swizzled LDS.
// ---------------------------------------------------------------------------
__global__ __launch_bounds__(256) void ffgemm_kernel(
    const ushort* __restrict__ featb, const ushort* __restrict__ Wbb,
    const float* __restrict__ bb, ushort* __restrict__ ffb)
{
    __shared__ __align__(16) ushort As[128][BK];  // 16 KB
    __shared__ __align__(16) ushort Bs[64][BK];   // 8 KB

    const int tid = threadIdx.x;
    const int lane = tid & 63, wid = tid >> 6;
    const int wm = wid >> 1, wn = wid & 1;
    const int i0 = blockIdx.y * 128;
    const int j0 = blockIdx.x * 64;
    const int csw  = (((lane & 7) ^ (lane >> 3)) * 8);
    const int rsub = lane >> 3;

    f32x4 acc[4][2] = {};

    for (int k0 = 0; k0 < H_; k0 += BK) {
#pragma unroll
        for (int cc = wid; cc < 24; cc += 4) {
            if (cc < 16) {
                const ushort* g = featb + (size_t)(i0 + cc*8 + rsub)*H_ + k0 + csw;
                gload16(g, &As[0][0] + cc*512);
            } else {
                const int c = cc - 16;
                const ushort* g = Wbb + (size_t)(j0 + c*8 + rsub)*H_ + k0 + csw;
                gload16(g, &Bs[0][0] + c*512);
            }
        }
        __syncthreads();
#pragma unroll
        for (int s = 0; s < 2; ++s) {
            const int colr = (((s*4 + (lane>>4)) ^ (lane & 7)) * 8);
            bf16x8 af[4];
#pragma unroll
            for (int fm = 0; fm < 4; ++fm)
                af[fm] = *(const bf16x8*)&As[wm*64 + fm*16 + (lane&15)][colr];
#pragma unroll
            for (int fn = 0; fn < 2; ++fn) {
                const bf16x8 bv = *(const bf16x8*)&Bs[wn*32 + fn*16 + (lane&15)][colr];
#pragma unroll
                for (int fm = 0; fm < 4; ++fm)
                    acc[fm][fn] = __builtin_amdgcn_mfma_f32_16x16x32_bf16(
                        af[fm], bv, acc[fm][fn], 0, 0, 0);
            }
        }
        __syncthreads();
    }

#pragma unroll
    for (int fn = 0; fn < 2; ++fn) {
        const int j = j0 + wn*32 + fn*16 + (lane & 15);
        const float b = bb[j];
#pragma unroll
        for (int fm = 0; fm < 4; ++fm)
#pragma unroll
            for (int r = 0; r < 4; ++r) {
                const int i = i0 + wm*64 + fm*16 + (lane >> 4)*4 + r;
                ffb[(size_t)i*H_ + j] = f2bf(tanhf_(acc[fm][fn][r] + b));
            }
    }
}

// ---------------------------------------------------------------------------
// logits[t*64+l, n] = ff[t*64+l,:] . V[n,:].  Swizzled LDS.
// ---------------------------------------------------------------------------
__global__ __launch_bounds__(256) void logits_kernel(
    const ushort* __restrict__ ffb, const ushort* __restrict__ dbb,
    const ushort* __restrict__ Kembb, float* __restrict__ logits)
{
    __shared__ __align__(16) ushort As[64][BK];   // 8 KB
    __shared__ __align__(16) ushort Bs[64][BK];   // 8 KB

    const int tid = threadIdx.x;
    const int lane = tid & 63, wid = tid >> 6;
    const int t = blockIdx.y;
    const int bx = blockIdx.x;
    const bool kw = (bx == 16);
    const int csw  = (((lane & 7) ^ (lane >> 3)) * 8);
    const int rsub = lane >> 3;

    f32x4 acc[4] = {};

    for (int k0 = 0; k0 < H_; k0 += BK) {
#pragma unroll
        for (int cc = wid; cc < 16; cc += 4) {
            if (cc < 8) {
                const ushort* g = ffb + (size_t)(t*64 + cc*8 + rsub)*H_ + k0 + csw;
                gload16(g, &As[0][0] + cc*512);
            } else {
                const int rloc = (cc-8)*8 + rsub;
                const ushort* g = kw ? (Kembb + (size_t)rloc*H_ + k0 + csw)
                                     : (dbb + (size_t)(t*U_ + bx*64 + rloc)*H_ + k0 + csw);
                gload16(g, &Bs[0][0] + (cc-8)*512);
            }
        }
        __syncthreads();
#pragma unroll
        for (int s = 0; s < 2; ++s) {
            const int colr = (((s*4 + (lane>>4)) ^ (lane & 7)) * 8);
            const bf16x8 af = *(const bf16x8*)&As[wid*16 + (lane&15)][colr];
#pragma unroll
            for (int fn = 0; fn < 4; ++fn) {
                const bf16x8 bv = *(const bf16x8*)&Bs[fn*16 + (lane&15)][colr];
                acc[fn] = __builtin_amdgcn_mfma_f32_16x16x32_bf16(af, bv, acc[fn], 0, 0, 0);
            }
        }
        __syncthreads();
    }

    const int ncols = U_ + K_;
#pragma unroll
    for (int fn = 0; fn < 4; ++fn) {
        const int jg = (kw ? U_ : bx*64) + fn*16 + (lane & 15);
#pragma unroll
        for (int r = 0; r < 4; ++r) {
            const int i = t*64 + wid*16 + (lane >> 4)*4 + r;
            logits[(size_t)i*ncols + jg] = acc[fn][r];
        }
    }
}

// ---------------------------------------------------------------------------
// per-row log_softmax over 1088 logits
// ---------------------------------------------------------------------------
__global__ __launch_bounds__(256) void lsm_kernel(
    const float* __restrict__ logits, float* __restrict__ out)
{
    __shared__ float sl[U_ + K_];
    __shared__ float red[4];
    const int row = blockIdx.x;
    const int tid = threadIdx.x;
    const int ncols = U_ + K_;

    float m = -3.4e38f;
    for (int idx = tid; idx < ncols; idx += 256) {
        const float v = logits[(size_t)row*ncols + idx];
        sl[idx] = v;
        m = fmaxf(m, v);
    }
    __syncthreads();
    m = block_reduce_max<256>(m, red);

    float s = 0.f;
    for (int idx = tid; idx < ncols; idx += 256) s += __expf(sl[idx] - m);
    s = block_reduce_sum<256>(s, red);
    const float lse = m + __logf(s);

    for (int idx = tid; idx < ncols; idx += 256)
        out[(size_t)row*ncols + idx] = sl[idx] - lse;
}

// ---------------------------------------------------------------------------
extern "C" void kernel_launch(void* const* d_in, const int* in_sizes, int n_in,
                              void* d_out, int out_size, void* d_ws, size_t ws_size,
                              hipStream_t stream)
{
    const float* feat  = (const float*)d_in[0];
    const float* key   = (const float*)d_in[1];
    const float* finf  = (const float*)d_in[2];
    const float* Wih_f = (const float*)d_in[3];
    const float* Whh_f = (const float*)d_in[4];
    const float* bih_f = (const float*)d_in[5];
    const float* bhh_f = (const float*)d_in[6];
    const float* Wih_b = (const float*)d_in[7];
    const float* Whh_b = (const float*)d_in[8];
    const float* bih_b = (const float*)d_in[9];
    const float* bhh_b = (const float*)d_in[10];
    const float* Wb    = (const float*)d_in[11];
    const float* bb    = (const float*)d_in[12];
    const float* Kemb  = (const float*)d_in[13];
    const int* col_idx  = (const int*)d_in[14];
    const int* col_mask = (const int*)d_in[15];
    const int* tab_idx  = (const int*)d_in[16];
    const int* tab_mask = (const int*)d_in[17];
    const int* attn_mask= (const int*)d_in[18];
    float* out = (float*)d_out;

    char* p = (char*)d_ws;
    ushort* wbf  = (ushort*)p;  p += (size_t)(2*(S0_+S1_) + WB_ + KE_)*2;  // 2.95 MB
    ushort* x1b  = (ushort*)p;  p += (size_t)M_*H_*2;                      // 16.8 MB
    ushort* x2b  = (ushort*)p;  p += (size_t)M_*H_*2;
    ushort* f1b  = (ushort*)p;  p += (size_t)M_*Hh_*2;
    ushort* b1b  = (ushort*)p;  p += (size_t)M_*Hh_*2;
    ushort* dbb  = (ushort*)p;  p += (size_t)M_*H_*2;                      // 16.8 MB
    float*  alog = (float*)p;   p += (size_t)T_*U_*4;
    float*  part = (float*)p;   p += (size_t)8*T_*H_*4;
    ushort* featb= (ushort*)p;  p += (size_t)T_*L_*H_*2;
    ushort* ffb  = (ushort*)p;  p += (size_t)T_*L_*H_*2;
    float*  lg   = (float*)p;   p += (size_t)T_*L_*(U_+K_)*4;              // 4.45 MB

    const ushort* Wihf_b = wbf;
    const ushort* Whhf_b = wbf + S0_;
    const ushort* Wihb_b = wbf + S0_ + S1_;
    const ushort* Whhb_b = wbf + 2*S0_ + S1_;
    const ushort* Wbb    = wbf + 2*(S0_ + S1_);
    const ushort* Kembb  = wbf + 2*(S0_ + S1_) + WB_;

    wcvt_kernel<<<(2*(S0_+S1_) + WB_ + KE_)/1024, 256, 0, stream>>>(
        Wih_f, Whh_f, Wih_b, Whh_b, Wb, Kemb, wbf);

    meanpool_kernel<<<dim3(U_/2, T_), 256, 0, stream>>>(
        feat, col_idx, col_mask, tab_idx, tab_mask, x1b, x2b);

    dim3 gg((M_/BM)*(Hh_/BNG), 1, 2);   // (1024, 1, 2), XCD-remapped in-kernel
    gru2_kernel<false><<<gg, 256, 0, stream>>>(
        x1b, x2b, nullptr, nullptr,
        Wihf_b, Wihb_b, Whhf_b, Whhb_b, bih_f, bih_b, bhh_f, bhh_b,
        f1b, b1b, nullptr, nullptr);
    gru2_kernel<true><<<gg, 256, 0, stream>>>(
        x2b, x1b, f1b, b1b,
        Wihf_b, Wihb_b, Whhf_b, Whhb_b, bih_f, bih_b, bhh_f, bhh_b,
        nullptr, nullptr, dbb, dbb + Hh_);

    attn_logits_kernel<<<dim3(16, T_), 256, 0, stream>>>(dbb, key, attn_mask, alog);
    attn_wsum_kernel<<<dim3(8, T_), 512, 0, stream>>>(dbb, alog, part);
    featcvt_kernel<<<T_*L_, 256, 0, stream>>>(finf, part, featb);
    ffgemm_kernel<<<dim3(H_/64, (T_*L_)/128), 256, 0, stream>>>(featb, Wbb, bb, ffb);
    logits_kernel<<<dim3(17, T_), 256, 0, stream>>>(ffb, dbb, Kembb, lg);
    lsm_kernel<<<T_*L_, 256, 0, stream>>>(lg, out);
}

// Round 13
// 253.460 us; speedup vs baseline: 1.0187x; 1.0034x over previous
//
#include <hip/hip_runtime.h>
#include <math.h>

#define T_  16
#define DB2_ 512
#define H_  512
#define Hh_ 256
#define U_  1024
#define MC_ 8
#define MT_ 4
#define L_  64
#define K_  64
#define M_  (T_*U_)   // 16384

#define BM 64
#define BNG 64
#define BK 64
#define S0_ (768*512)
#define S1_ (768*256)
#define WB_ (512*512)
#define KE_ (64*512)

typedef __attribute__((ext_vector_type(8))) short bf16x8;
typedef __attribute__((ext_vector_type(4))) float f32x4;

__device__ __forceinline__ float sigmoidf_(float x) {
    return 1.f / (1.f + __expf(-x));
}
__device__ __forceinline__ float tanhf_(float x) {
    const float xc = fminf(fmaxf(x, -10.f), 10.f);
    const float t = __expf(2.f * xc);
    return (t - 1.f) / (t + 1.f);
}

__device__ __forceinline__ ushort f2bf(float f) {
    union { float f; unsigned u; } v; v.f = f;
    const unsigned r = (v.u + 0x7FFFu + ((v.u >> 16) & 1u)) >> 16;
    return (ushort)r;
}
__device__ __forceinline__ float bf2f(ushort u) {
    union { unsigned u; float f; } v; v.u = ((unsigned)u) << 16; return v.f;
}

__device__ __forceinline__ void gload16(const void* g, void* l) {
    __builtin_amdgcn_global_load_lds(
        (const __attribute__((address_space(1))) void*)g,
        (__attribute__((address_space(3))) void*)l, 16, 0, 0);
}

// ---------------------------------------------------------------------------
// Kernel 0: convert weights to bf16: Wih_f|Whh_f|Wih_b|Whh_b|Wb|Kemb
// ---------------------------------------------------------------------------
__global__ __launch_bounds__(256) void wcvt_kernel(
    const float* __restrict__ w0, const float* __restrict__ w1,
    const float* __restrict__ w2, const float* __restrict__ w3,
    const float* __restrict__ w4, const float* __restrict__ w5,
    ushort* __restrict__ dst)
{
    const int idx = (blockIdx.x * 256 + threadIdx.x) * 4;
    const float* src; int local;
    if      (idx < S0_)                  { src = w0; local = idx; }
    else if (idx < S0_ + S1_)            { src = w1; local = idx - S0_; }
    else if (idx < 2*S0_ + S1_)          { src = w2; local = idx - S0_ - S1_; }
    else if (idx < 2*S0_ + 2*S1_)        { src = w3; local = idx - 2*S0_ - S1_; }
    else if (idx < 2*S0_ + 2*S1_ + WB_)  { src = w4; local = idx - 2*S0_ - 2*S1_; }
    else                                 { src = w5; local = idx - 2*S0_ - 2*S1_ - WB_; }
    const float4 v = *(const float4*)(src + local);
    ushort4 o; o.x = f2bf(v.x); o.y = f2bf(v.y); o.z = f2bf(v.z); o.w = f2bf(v.w);
    *(ushort4*)(dst + idx) = o;
}

// ---------------------------------------------------------------------------
// Kernel 1: masked mean pooling -> x1 (tab), x2 (col) in bf16.
// float4 loads, 2 u per block. Flat 8192-block grid, remapped so all blocks
// of time-step t land on XCD t%8 (2 t-slices = 2MB < 4MB L2 per XCD):
//   L = u2*16 + (t>>3)*8 + (t&7)  =>  t = (L&7) + 8*((L>>3)&1), u2 = L>>4.
// ---------------------------------------------------------------------------
__global__ __launch_bounds__(256) void meanpool_kernel(
    const float* __restrict__ feat,
    const int* __restrict__ col_idx, const int* __restrict__ col_mask,
    const int* __restrict__ tab_idx, const int* __restrict__ tab_mask,
    ushort* __restrict__ x1, ushort* __restrict__ x2)
{
    const int tid = threadIdx.x;
    const int L = blockIdx.x;
    const int t  = (L & 7) + 8*((L >> 3) & 1);
    const int u2 = L >> 4;
    const int u = u2*2 + (tid >> 7);
    const int h = (tid & 127) * 4;

    int ci[MC_], cm[MC_], ti[MT_], tm[MT_];
    float cc = 0.f, tc = 0.f;
#pragma unroll
    for (int m = 0; m < MC_; ++m) { ci[m] = col_idx[u*MC_+m]; cm[m] = col_mask[u*MC_+m]; cc += (float)cm[m]; }
#pragma unroll
    for (int m = 0; m < MT_; ++m) { ti[m] = tab_idx[u*MT_+m]; tm[m] = tab_mask[u*MT_+m]; tc += (float)tm[m]; }
    const float rc = 1.f / fmaxf(cc, 1.f);
    const float rt = 1.f / fmaxf(tc, 1.f);

    const float* fb = feat + (size_t)t * DB2_ * H_;

    float4 ac = make_float4(0.f,0.f,0.f,0.f), at = make_float4(0.f,0.f,0.f,0.f);
#pragma unroll
    for (int m = 0; m < MC_; ++m) if (cm[m]) {
        const float4 v = *(const float4*)(fb + (size_t)ci[m]*H_ + h);
        ac.x += v.x; ac.y += v.y; ac.z += v.z; ac.w += v.w;
    }
#pragma unroll
    for (int m = 0; m < MT_; ++m) if (tm[m]) {
        const float4 v = *(const float4*)(fb + (size_t)ti[m]*H_ + h);
        at.x += v.x; at.y += v.y; at.z += v.z; at.w += v.w;
    }
    const size_t o = ((size_t)(t*U_ + u))*H_ + h;
    ushort4 c4; c4.x = f2bf(ac.x*rc); c4.y = f2bf(ac.y*rc); c4.z = f2bf(ac.z*rc); c4.w = f2bf(ac.w*rc);
    ushort4 t4; t4.x = f2bf(at.x*rt); t4.y = f2bf(at.y*rt); t4.z = f2bf(at.z*rt); t4.w = f2bf(at.w*rt);
    *(ushort4*)(x2 + o) = c4;
    *(ushort4*)(x1 + o) = t4;
}

// ---------------------------------------------------------------------------
// GRU cells via MFMA, swizzled LDS.  BM=64, 4 waves of 32x32x3gates.
// R10 structure (measured best): single buffer, hoisted loop-carried pointers,
// __syncthreads; unified-regfile cap (64 VGPR + 64 AGPR acc) => 4 waves/SIMD.
// blockIdx.x XCD-remapped.
// ---------------------------------------------------------------------------
template<int GN>
__device__ __forceinline__ void compute_tile64(
    f32x4 (&acc)[4][2][2],
    const ushort (&As)[BM][BK], const ushort (&Bs)[192][BK],
    int lane, int wm, int wn)
{
#pragma unroll
    for (int s = 0; s < 2; ++s) {
        const int colr = (((s*4 + (lane>>4)) ^ (lane & 7)) * 8);  // swizzled read col
        bf16x8 af[2];
#pragma unroll
        for (int fm = 0; fm < 2; ++fm)
            af[fm] = *(const bf16x8*)&As[wm*32 + fm*16 + (lane&15)][colr];
#pragma unroll
        for (int g = 0; g < 3; ++g) {
            const int gi = (g == 2) ? GN : g;
#pragma unroll
            for (int fn = 0; fn < 2; ++fn) {
                const bf16x8 bv = *(const bf16x8*)&Bs[g*64 + wn*32 + fn*16 + (lane&15)][colr];
#pragma unroll
                for (int fm = 0; fm < 2; ++fm)
                    acc[gi][fm][fn] = __builtin_amdgcn_mfma_f32_16x16x32_bf16(
                        af[fm], bv, acc[gi][fm][fn], 0, 0, 0);
            }
        }
    }
}

template<bool HAS_H>
__global__ __launch_bounds__(256, 4) void gru2_kernel(
    const ushort* __restrict__ X0, const ushort* __restrict__ X1,
    const ushort* __restrict__ Hb0, const ushort* __restrict__ Hb1,
    const ushort* __restrict__ Wih0, const ushort* __restrict__ Wih1,
    const ushort* __restrict__ Whh0, const ushort* __restrict__ Whh1,
    const float* __restrict__ bih0, const float* __restrict__ bih1,
    const float* __restrict__ bhh0, const float* __restrict__ bhh1,
    ushort* __restrict__ HoutB0, ushort* __restrict__ HoutB1,
    ushort* __restrict__ emb0, ushort* __restrict__ emb1)
{
    __shared__ __align__(16) ushort As[BM][BK];   // 8 KB
    __shared__ __align__(16) ushort Bs[192][BK];  // 24 KB

    const int sel = blockIdx.z;
    const ushort* Xb   = sel ? X1 : X0;
    const ushort* Hb   = sel ? Hb1 : Hb0;
    const ushort* Wihb = sel ? Wih1 : Wih0;
    const ushort* Whhb = sel ? Whh1 : Whh0;
    const float*  bih  = sel ? bih1 : bih0;
    const float*  bhh  = sel ? bhh1 : bhh0;
    ushort* Hout_b = sel ? HoutB1 : HoutB0;
    ushort* emb_b  = sel ? emb1 : emb0;

    const int tid = threadIdx.x;
    const int lane = tid & 63, wid = tid >> 6;
    const int wm = wid >> 1, wn = wid & 1;

    // XCD remap: flat = ((ib/8)*4 + jb)*8 + ib%8  (bijective on [0,1024))
    const int flat = blockIdx.x;
    const int i8   = flat & 7;
    const int rest = flat >> 3;
    const int jb   = rest & 3;
    const int ib   = (rest >> 2) * 8 + i8;
    const int i0 = ib * BM;
    const int j0 = jb * BNG;

    const int csw  = (((lane & 7) ^ (lane >> 3)) * 8);
    const int rsub = lane >> 3;

    // fixed wave-uniform LDS destinations
    ushort* const ldsA0 = &As[0][0] + (size_t)wid*512;
    ushort* const ldsA1 = &As[0][0] + (size_t)(wid+4)*512;
    ushort* ldsB[6];
#pragma unroll
    for (int s = 0; s < 6; ++s) ldsB[s] = &Bs[0][0] + (size_t)(wid + 4*s)*512;

    f32x4 acc[4][2][2] = {};   // [r,z,n_ih | n_hh][fm][fn]

    // ---- phase 1: X @ Wih^T ----
    {
        const ushort* ga0 = Xb + (size_t)(i0 + wid*8     + rsub)*H_ + csw;
        const ushort* ga1 = Xb + (size_t)(i0 + (wid+4)*8 + rsub)*H_ + csw;
        const ushort* gb[6];
#pragma unroll
        for (int s = 0; s < 6; ++s) {
            const int rowB = (wid + 4*s)*8 + rsub;
            gb[s] = Wihb + (size_t)((rowB>>6)*Hh_ + j0 + (rowB&63))*H_ + csw;
        }
        for (int k0 = 0; k0 < H_; k0 += BK) {
            gload16(ga0, ldsA0);
            gload16(ga1, ldsA1);
#pragma unroll
            for (int s = 0; s < 6; ++s) gload16(gb[s], ldsB[s]);
            ga0 += BK; ga1 += BK;
#pragma unroll
            for (int s = 0; s < 6; ++s) gb[s] += BK;
            __syncthreads();
            compute_tile64<2>(acc, As, Bs, lane, wm, wn);
            __syncthreads();
        }
    }
    // ---- phase 2: H @ Whh^T ----
    if (HAS_H) {
        const ushort* ga0 = Hb + (size_t)(i0 + wid*8     + rsub)*Hh_ + csw;
        const ushort* ga1 = Hb + (size_t)(i0 + (wid+4)*8 + rsub)*Hh_ + csw;
        const ushort* gb[6];
#pragma unroll
        for (int s = 0; s < 6; ++s) {
            const int rowB = (wid + 4*s)*8 + rsub;
            gb[s] = Whhb + (size_t)((rowB>>6)*Hh_ + j0 + (rowB&63))*Hh_ + csw;
        }
        for (int k0 = 0; k0 < Hh_; k0 += BK) {
            gload16(ga0, ldsA0);
            gload16(ga1, ldsA1);
#pragma unroll
            for (int s = 0; s < 6; ++s) gload16(gb[s], ldsB[s]);
            ga0 += BK; ga1 += BK;
#pragma unroll
            for (int s = 0; s < 6; ++s) gb[s] += BK;
            __syncthreads();
            compute_tile64<3>(acc, As, Bs, lane, wm, wn);
            __syncthreads();
        }
    }

#pragma unroll
    for (int fn = 0; fn < 2; ++fn) {
        const int j = j0 + wn*32 + fn*16 + (lane & 15);
        const float bri = bih[j],       brh = bhh[j];
        const float bzi = bih[Hh_ + j], bzh = bhh[Hh_ + j];
        const float bni = bih[2*Hh_+j], bnh = bhh[2*Hh_ + j];
#pragma unroll
        for (int fm = 0; fm < 2; ++fm) {
#pragma unroll
            for (int r = 0; r < 4; ++r) {
                const int i = i0 + wm*32 + fm*16 + (lane >> 4)*4 + r;
                const float xr = acc[0][fm][fn][r] + bri + brh;
                const float xz = acc[1][fm][fn][r] + bzi + bzh;
                const float xn = acc[2][fm][fn][r] + bni;
                float hn = bnh, hprev = 0.f;
                if (HAS_H) { hn += acc[3][fm][fn][r]; hprev = bf2f(Hb[(size_t)i*Hh_ + j]); }
                const float rg = sigmoidf_(xr);
                const float zg = sigmoidf_(xz);
                const float ng = tanhf_(xn + rg * hn);
                const float hp = (1.f - zg) * ng + zg * hprev;
                if (HAS_H) {
                    emb_b[(size_t)i*H_ + j] = f2bf(0.5f * (hprev + hp));
                } else {
                    Hout_b[(size_t)i*Hh_ + j] = f2bf(hp);
                }
            }
        }
    }
}

// ---------------------------------------------------------------------------
// block reductions
// ---------------------------------------------------------------------------
template<int NT>
__device__ __forceinline__ float block_reduce_max(float v, float* red) {
#pragma unroll
    for (int o = 32; o > 0; o >>= 1) v = fmaxf(v, __shfl_down(v, o));
    const int wid = threadIdx.x >> 6;
    if ((threadIdx.x & 63) == 0) red[wid] = v;
    __syncthreads();
    if (threadIdx.x == 0) {
        float m = red[0];
#pragma unroll
        for (int i = 1; i < NT/64; ++i) m = fmaxf(m, red[i]);
        red[0] = m;
    }
    __syncthreads();
    const float r = red[0];
    __syncthreads();
    return r;
}

template<int NT>
__device__ __forceinline__ float block_reduce_sum(float v, float* red) {
#pragma unroll
    for (int o = 32; o > 0; o >>= 1) v += __shfl_down(v, o);
    const int wid = threadIdx.x >> 6;
    if ((threadIdx.x & 63) == 0) red[wid] = v;
    __syncthreads();
    if (threadIdx.x == 0) {
        float m = red[0];
#pragma unroll
        for (int i = 1; i < NT/64; ++i) m += red[i];
        red[0] = m;
    }
    __syncthreads();
    const float r = red[0];
    __syncthreads();
    return r;
}

// ---------------------------------------------------------------------------
// attention.
// A: logits.  grid (16, T), 256 threads: 64 u/block, 4 threads per u.
// ---------------------------------------------------------------------------
__global__ __launch_bounds__(256) void attn_logits_kernel(
    const ushort* __restrict__ db, const float* __restrict__ key,
    const int* __restrict__ attn_mask, float* __restrict__ alog)
{
    const int t = blockIdx.y;
    const int tid = threadIdx.x;
    const int u = blockIdx.x*64 + (tid >> 2);
    const int kq = (tid & 3) * 128;

    const bf16x8* r8 = (const bf16x8*)(db + ((size_t)t*U_ + u)*H_ + kq);
    const float* kp = key + t*H_ + kq;
    float s = 0.f;
#pragma unroll
    for (int k8 = 0; k8 < 16; ++k8) {
        const bf16x8 v = r8[k8];
#pragma unroll
        for (int j = 0; j < 8; ++j)
            s = fmaf(kp[k8*8 + j], bf2f((ushort)v[j]), s);
    }
    s += __shfl_xor(s, 1);
    s += __shfl_xor(s, 2);
    if ((tid & 3) == 0)
        alog[t*U_ + u] = attn_mask[t*U_ + u] ? s : -1e9f;
}

// B: weighted sum partials with INLINE softmax (each block recomputes m,s from
// the 4KB alog row — cheaper than a separate 16-block kernel launch).
// grid (8, T), 512 threads = 8 u-slices x 64 h-octets.
__global__ __launch_bounds__(512) void attn_wsum_kernel(
    const ushort* __restrict__ db, const float* __restrict__ alog,
    float* __restrict__ part)
{
    __shared__ float sred[8][64][8];   // 16 KB
    __shared__ float red[8];
    const int t = blockIdx.y, u0 = blockIdx.x * 128;
    const int tid = threadIdx.x;

    // softmax stats over the full row (all 1024 u), 2 values per thread
    const float v0 = alog[t*U_ + tid], v1 = alog[t*U_ + tid + 512];
    const float m = block_reduce_max<512>(fmaxf(v0, v1), red);
    const float ssum = block_reduce_sum<512>(__expf(v0 - m) + __expf(v1 - m), red);
    const float inv = 1.f / ssum;

    const int usub = tid >> 6;   // 0..7
    const int h8   = tid & 63;   // 0..63

    float a[8] = {};
    for (int uu = 0; uu < 16; ++uu) {
        const int u = u0 + usub*16 + uu;
        const float w = __expf(alog[t*U_ + u] - m) * inv;
        const bf16x8 v = *(const bf16x8*)(db + ((size_t)t*U_ + u)*H_ + h8*8);
#pragma unroll
        for (int j = 0; j < 8; ++j) a[j] = fmaf(w, bf2f((ushort)v[j]), a[j]);
    }
#pragma unroll
    for (int j = 0; j < 8; ++j) sred[usub][h8][j] = a[j];
    __syncthreads();

    const int h8r = tid >> 3;    // 0..63
    const int cr  = tid & 7;     // 0..7
    float s = 0.f;
#pragma unroll
    for (int us = 0; us < 8; ++us) s += sred[us][h8r][cr];
    part[((size_t)blockIdx.x*T_ + t)*H_ + h8r*8 + cr] = s;
}

// ---------------------------------------------------------------------------
// feature = finf + sum(part) -> bf16
// ---------------------------------------------------------------------------
__global__ __launch_bounds__(256) void featcvt_kernel(
    const float* __restrict__ finf, const float* __restrict__ part,
    ushort* __restrict__ featb)
{
    const int row = blockIdx.x;       // t*64+l
    const int t = row >> 6;
    const int h = threadIdx.x * 2;
    const float2 v = *(const float2*)(finf + (size_t)row*H_ + h);
    float ax = 0.f, ay = 0.f;
#pragma unroll
    for (int p = 0; p < 8; ++p) {
        const float2 a = *(const float2*)(part + ((size_t)p*T_ + t)*H_ + h);
        ax += a.x; ay += a.y;
    }
    ushort2 o; o.x = f2bf(v.x + ax); o.y = f2bf(v.y + ay);
    *(ushort2*)(featb + (size_t)row*H_ + h) = o;
}

// ---------------------------------------------------------------------------
// ff = tanh(featb @ Wb^T + bb) -> bf16.  M=1024, N=512, K=512. Swizzled LDS.
// ---------------------------------------------------------------------------
__global__ __launch_bounds__(256) void ffgemm_kernel(
    const ushort* __restrict__ featb, const ushort* __restrict__ Wbb,
    const float* __restrict__ bb, ushort* __restrict__ ffb)
{
    __shared__ __align__(16) ushort As[128][BK];  // 16 KB
    __shared__ __align__(16) ushort Bs[64][BK];   // 8 KB

    const int tid = threadIdx.x;
    const int lane = tid & 63, wid = tid >> 6;
    const int wm = wid >> 1, wn = wid & 1;
    const int i0 = blockIdx.y * 128;
    const int j0 = blockIdx.x * 64;
    const int csw  = (((lane & 7) ^ (lane >> 3)) * 8);
    const int rsub = lane >> 3;

    f32x4 acc[4][2] = {};

    for (int k0 = 0; k0 < H_; k0 += BK) {
#pragma unroll
        for (int cc = wid; cc < 24; cc += 4) {
            if (cc < 16) {
                const ushort* g = featb + (size_t)(i0 + cc*8 + rsub)*H_ + k0 + csw;
                gload16(g, &As[0][0] + cc*512);
            } else {
                const int c = cc - 16;
                const ushort* g = Wbb + (size_t)(j0 + c*8 + rsub)*H_ + k0 + csw;
                gload16(g, &Bs[0][0] + c*512);
            }
        }
        __syncthreads();
#pragma unroll
        for (int s = 0; s < 2; ++s) {
            const int colr = (((s*4 + (lane>>4)) ^ (lane & 7)) * 8);
            bf16x8 af[4];
#pragma unroll
            for (int fm = 0; fm < 4; ++fm)
                af[fm] = *(const bf16x8*)&As[wm*64 + fm*16 + (lane&15)][colr];
#pragma unroll
            for (int fn = 0; fn < 2; ++fn) {
                const bf16x8 bv = *(const bf16x8*)&Bs[wn*32 + fn*16 + (lane&15)][colr];
#pragma unroll
                for (int fm = 0; fm < 4; ++fm)
                    acc[fm][fn] = __builtin_amdgcn_mfma_f32_16x16x32_bf16(
                        af[fm], bv, acc[fm][fn], 0, 0, 0);
            }
        }
        __syncthreads();
    }

#pragma unroll
    for (int fn = 0; fn < 2; ++fn) {
        const int j = j0 + wn*32 + fn*16 + (lane & 15);
        const float b = bb[j];
#pragma unroll
        for (int fm = 0; fm < 4; ++fm)
#pragma unroll
            for (int r = 0; r < 4; ++r) {
                const int i = i0 + wm*64 + fm*16 + (lane >> 4)*4 + r;
                ffb[(size_t)i*H_ + j] = f2bf(tanhf_(acc[fm][fn][r] + b));
            }
    }
}

// ---------------------------------------------------------------------------
// logits[t*64+l, n] = ff[t*64+l,:] . V[n,:].  Swizzled LDS.
// ---------------------------------------------------------------------------
__global__ __launch_bounds__(256) void logits_kernel(
    const ushort* __restrict__ ffb, const ushort* __restrict__ dbb,
    const ushort* __restrict__ Kembb, float* __restrict__ logits)
{
    __shared__ __align__(16) ushort As[64][BK];   // 8 KB
    __shared__ __align__(16) ushort Bs[64][BK];   // 8 KB

    const int tid = threadIdx.x;
    const int lane = tid & 63, wid = tid >> 6;
    const int t = blockIdx.y;
    const int bx = blockIdx.x;
    const bool kw = (bx == 16);
    const int csw  = (((lane & 7) ^ (lane >> 3)) * 8);
    const int rsub = lane >> 3;

    f32x4 acc[4] = {};

    for (int k0 = 0; k0 < H_; k0 += BK) {
#pragma unroll
        for (int cc = wid; cc < 16; cc += 4) {
            if (cc < 8) {
                const ushort* g = ffb + (size_t)(t*64 + cc*8 + rsub)*H_ + k0 + csw;
                gload16(g, &As[0][0] + cc*512);
            } else {
                const int rloc = (cc-8)*8 + rsub;
                const ushort* g = kw ? (Kembb + (size_t)rloc*H_ + k0 + csw)
                                     : (dbb + (size_t)(t*U_ + bx*64 + rloc)*H_ + k0 + csw);
                gload16(g, &Bs[0][0] + (cc-8)*512);
            }
        }
        __syncthreads();
#pragma unroll
        for (int s = 0; s < 2; ++s) {
            const int colr = (((s*4 + (lane>>4)) ^ (lane & 7)) * 8);
            const bf16x8 af = *(const bf16x8*)&As[wid*16 + (lane&15)][colr];
#pragma unroll
            for (int fn = 0; fn < 4; ++fn) {
                const bf16x8 bv = *(const bf16x8*)&Bs[fn*16 + (lane&15)][colr];
                acc[fn] = __builtin_amdgcn_mfma_f32_16x16x32_bf16(af, bv, acc[fn], 0, 0, 0);
            }
        }
        __syncthreads();
    }

    const int ncols = U_ + K_;
#pragma unroll
    for (int fn = 0; fn < 4; ++fn) {
        const int jg = (kw ? U_ : bx*64) + fn*16 + (lane & 15);
#pragma unroll
        for (int r = 0; r < 4; ++r) {
            const int i = t*64 + wid*16 + (lane >> 4)*4 + r;
            logits[(size_t)i*ncols + jg] = acc[fn][r];
        }
    }
}

// ---------------------------------------------------------------------------
// per-row log_softmax over 1088 logits
// ---------------------------------------------------------------------------
__global__ __launch_bounds__(256) void lsm_kernel(
    const float* __restrict__ logits, float* __restrict__ out)
{
    __shared__ float sl[U_ + K_];
    __shared__ float red[4];
    const int row = blockIdx.x;
    const int tid = threadIdx.x;
    const int ncols = U_ + K_;

    float m = -3.4e38f;
    for (int idx = tid; idx < ncols; idx += 256) {
        const float v = logits[(size_t)row*ncols + idx];
        sl[idx] = v;
        m = fmaxf(m, v);
    }
    __syncthreads();
    m = block_reduce_max<256>(m, red);

    float s = 0.f;
    for (int idx = tid; idx < ncols; idx += 256) s += __expf(sl[idx] - m);
    s = block_reduce_sum<256>(s, red);
    const float lse = m + __logf(s);

    for (int idx = tid; idx < ncols; idx += 256)
        out[(size_t)row*ncols + idx] = sl[idx] - lse;
}

// ---------------------------------------------------------------------------
extern "C" void kernel_launch(void* const* d_in, const int* in_sizes, int n_in,
                              void* d_out, int out_size, void* d_ws, size_t ws_size,
                              hipStream_t stream)
{
    const float* feat  = (const float*)d_in[0];
    const float* key   = (const float*)d_in[1];
    const float* finf  = (const float*)d_in[2];
    const float* Wih_f = (const float*)d_in[3];
    const float* Whh_f = (const float*)d_in[4];
    const float* bih_f = (const float*)d_in[5];
    const float* bhh_f = (const float*)d_in[6];
    const float* Wih_b = (const float*)d_in[7];
    const float* Whh_b = (const float*)d_in[8];
    const float* bih_b = (const float*)d_in[9];
    const float* bhh_b = (const float*)d_in[10];
    const float* Wb    = (const float*)d_in[11];
    const float* bb    = (const float*)d_in[12];
    const float* Kemb  = (const float*)d_in[13];
    const int* col_idx  = (const int*)d_in[14];
    const int* col_mask = (const int*)d_in[15];
    const int* tab_idx  = (const int*)d_in[16];
    const int* tab_mask = (const int*)d_in[17];
    const int* attn_mask= (const int*)d_in[18];
    float* out = (float*)d_out;

    char* p = (char*)d_ws;
    ushort* wbf  = (ushort*)p;  p += (size_t)(2*(S0_+S1_) + WB_ + KE_)*2;  // 2.95 MB
    ushort* x1b  = (ushort*)p;  p += (size_t)M_*H_*2;                      // 16.8 MB
    ushort* x2b  = (ushort*)p;  p += (size_t)M_*H_*2;
    ushort* f1b  = (ushort*)p;  p += (size_t)M_*Hh_*2;
    ushort* b1b  = (ushort*)p;  p += (size_t)M_*Hh_*2;
    ushort* dbb  = (ushort*)p;  p += (size_t)M_*H_*2;                      // 16.8 MB
    float*  alog = (float*)p;   p += (size_t)T_*U_*4;
    float*  part = (float*)p;   p += (size_t)8*T_*H_*4;
    ushort* featb= (ushort*)p;  p += (size_t)T_*L_*H_*2;
    ushort* ffb  = (ushort*)p;  p += (size_t)T_*L_*H_*2;
    float*  lg   = (float*)p;   p += (size_t)T_*L_*(U_+K_)*4;              // 4.45 MB

    const ushort* Wihf_b = wbf;
    const ushort* Whhf_b = wbf + S0_;
    const ushort* Wihb_b = wbf + S0_ + S1_;
    const ushort* Whhb_b = wbf + 2*S0_ + S1_;
    const ushort* Wbb    = wbf + 2*(S0_ + S1_);
    const ushort* Kembb  = wbf + 2*(S0_ + S1_) + WB_;

    wcvt_kernel<<<(2*(S0_+S1_) + WB_ + KE_)/1024, 256, 0, stream>>>(
        Wih_f, Whh_f, Wih_b, Whh_b, Wb, Kemb, wbf);

    meanpool_kernel<<<(U_/2)*T_, 256, 0, stream>>>(
        feat, col_idx, col_mask, tab_idx, tab_mask, x1b, x2b);

    dim3 gg((M_/BM)*(Hh_/BNG), 1, 2);   // (1024, 1, 2), XCD-remapped in-kernel
    gru2_kernel<false><<<gg, 256, 0, stream>>>(
        x1b, x2b, nullptr, nullptr,
        Wihf_b, Wihb_b, Whhf_b, Whhb_b, bih_f, bih_b, bhh_f, bhh_b,
        f1b, b1b, nullptr, nullptr);
    gru2_kernel<true><<<gg, 256, 0, stream>>>(
        x2b, x1b, f1b, b1b,
        Wihf_b, Wihb_b, Whhf_b, Whhb_b, bih_f, bih_b, bhh_f, bhh_b,
        nullptr, nullptr, dbb, dbb + Hh_);

    attn_logits_kernel<<<dim3(16, T_), 256, 0, stream>>>(dbb, key, attn_mask, alog);
    attn_wsum_kernel<<<dim3(8, T_), 512, 0, stream>>>(dbb, alog, part);
    featcvt_kernel<<<T_*L_, 256, 0, stream>>>(finf, part, featb);
    ffgemm_kernel<<<dim3(H_/64, (T_*L_)/128), 256, 0, stream>>>(featb, Wbb, bb, ffb);
    logits_kernel<<<dim3(17, T_), 256, 0, stream>>>(ffb, dbb, Kembb, lg);
    lsm_kernel<<<T_*L_, 256, 0, stream>>>(lg, out);
}

// Round 14
// 251.012 us; speedup vs baseline: 1.0287x; 1.0098x over previous
//
#include <hip/hip_runtime.h>
#include <math.h>

#define T_  16
#define DB2_ 512
#define H_  512
#define Hh_ 256
#define U_  1024
#define MC_ 8
#define MT_ 4
#define L_  64
#define K_  64
#define M_  (T_*U_)   // 16384

#define BM 64
#define BNG 64
#define BK 64
#define S0_ (768*512)
#define S1_ (768*256)
#define WB_ (512*512)
#define KE_ (64*512)
#define NWCVT_ ((2*(S0_+S1_) + WB_ + KE_)/1024)   // 1440 blocks

typedef __attribute__((ext_vector_type(8))) short bf16x8;
typedef __attribute__((ext_vector_type(4))) float f32x4;

__device__ __forceinline__ float sigmoidf_(float x) {
    return 1.f / (1.f + __expf(-x));
}
__device__ __forceinline__ float tanhf_(float x) {
    const float xc = fminf(fmaxf(x, -10.f), 10.f);
    const float t = __expf(2.f * xc);
    return (t - 1.f) / (t + 1.f);
}

__device__ __forceinline__ ushort f2bf(float f) {
    union { float f; unsigned u; } v; v.f = f;
    const unsigned r = (v.u + 0x7FFFu + ((v.u >> 16) & 1u)) >> 16;
    return (ushort)r;
}
__device__ __forceinline__ float bf2f(ushort u) {
    union { unsigned u; float f; } v; v.u = ((unsigned)u) << 16; return v.f;
}

__device__ __forceinline__ void gload16(const void* g, void* l) {
    __builtin_amdgcn_global_load_lds(
        (const __attribute__((address_space(1))) void*)g,
        (__attribute__((address_space(3))) void*)l, 16, 0, 0);
}

// ---------------------------------------------------------------------------
// Kernel 1 (merged): blocks [0,NWCVT_) = weight bf16 convert;
// blocks [NWCVT_, NWCVT_+8192) = masked mean pooling (independent work,
// merged to overlap and save a launch).
// ---------------------------------------------------------------------------
__global__ __launch_bounds__(256) void pre_kernel(
    const float* __restrict__ w0, const float* __restrict__ w1,
    const float* __restrict__ w2, const float* __restrict__ w3,
    const float* __restrict__ w4, const float* __restrict__ w5,
    ushort* __restrict__ dst,
    const float* __restrict__ feat,
    const int* __restrict__ col_idx, const int* __restrict__ col_mask,
    const int* __restrict__ tab_idx, const int* __restrict__ tab_mask,
    ushort* __restrict__ x1, ushort* __restrict__ x2)
{
    const int tid = threadIdx.x;
    if (blockIdx.x < NWCVT_) {
        // ---- weight convert ----
        const int idx = (blockIdx.x * 256 + tid) * 4;
        const float* src; int local;
        if      (idx < S0_)                  { src = w0; local = idx; }
        else if (idx < S0_ + S1_)            { src = w1; local = idx - S0_; }
        else if (idx < 2*S0_ + S1_)          { src = w2; local = idx - S0_ - S1_; }
        else if (idx < 2*S0_ + 2*S1_)        { src = w3; local = idx - 2*S0_ - S1_; }
        else if (idx < 2*S0_ + 2*S1_ + WB_)  { src = w4; local = idx - 2*S0_ - 2*S1_; }
        else                                 { src = w5; local = idx - 2*S0_ - 2*S1_ - WB_; }
        const float4 v = *(const float4*)(src + local);
        ushort4 o; o.x = f2bf(v.x); o.y = f2bf(v.y); o.z = f2bf(v.z); o.w = f2bf(v.w);
        *(ushort4*)(dst + idx) = o;
        return;
    }
    // ---- mean pooling: 2 u per block, float4 loads ----
    const int Lb = blockIdx.x - NWCVT_;
    const int t  = (Lb & 7) + 8*((Lb >> 3) & 1);
    const int u2 = Lb >> 4;
    const int u = u2*2 + (tid >> 7);
    const int h = (tid & 127) * 4;

    int ci[MC_], cm[MC_], ti[MT_], tm[MT_];
    float cc = 0.f, tc = 0.f;
#pragma unroll
    for (int m = 0; m < MC_; ++m) { ci[m] = col_idx[u*MC_+m]; cm[m] = col_mask[u*MC_+m]; cc += (float)cm[m]; }
#pragma unroll
    for (int m = 0; m < MT_; ++m) { ti[m] = tab_idx[u*MT_+m]; tm[m] = tab_mask[u*MT_+m]; tc += (float)tm[m]; }
    const float rc = 1.f / fmaxf(cc, 1.f);
    const float rt = 1.f / fmaxf(tc, 1.f);

    const float* fb = feat + (size_t)t * DB2_ * H_;

    float4 ac = make_float4(0.f,0.f,0.f,0.f), at = make_float4(0.f,0.f,0.f,0.f);
#pragma unroll
    for (int m = 0; m < MC_; ++m) if (cm[m]) {
        const float4 v = *(const float4*)(fb + (size_t)ci[m]*H_ + h);
        ac.x += v.x; ac.y += v.y; ac.z += v.z; ac.w += v.w;
    }
#pragma unroll
    for (int m = 0; m < MT_; ++m) if (tm[m]) {
        const float4 v = *(const float4*)(fb + (size_t)ti[m]*H_ + h);
        at.x += v.x; at.y += v.y; at.z += v.z; at.w += v.w;
    }
    const size_t o = ((size_t)(t*U_ + u))*H_ + h;
    ushort4 c4; c4.x = f2bf(ac.x*rc); c4.y = f2bf(ac.y*rc); c4.z = f2bf(ac.z*rc); c4.w = f2bf(ac.w*rc);
    ushort4 t4; t4.x = f2bf(at.x*rt); t4.y = f2bf(at.y*rt); t4.z = f2bf(at.z*rt); t4.w = f2bf(at.w*rt);
    *(ushort4*)(x2 + o) = c4;
    *(ushort4*)(x1 + o) = t4;
}

// ---------------------------------------------------------------------------
// GRU cells via MFMA, swizzled LDS.  BM=64, 4 waves of 32x32x3gates.
// R10 K-loop (measured best). Epilogue now stages the 64x64 bf16 output
// tile in padded LDS [64][72] and stores coalesced bf16x8 (128B/row chunks)
// -- fixes WRITE_SIZE 24.5MB vs ideal 16.8MB (partial-line RMW).
// ---------------------------------------------------------------------------
template<int GN>
__device__ __forceinline__ void compute_tile64(
    f32x4 (&acc)[4][2][2],
    const ushort (&As)[BM][BK], const ushort (&Bs)[192][BK],
    int lane, int wm, int wn)
{
#pragma unroll
    for (int s = 0; s < 2; ++s) {
        const int colr = (((s*4 + (lane>>4)) ^ (lane & 7)) * 8);  // swizzled read col
        bf16x8 af[2];
#pragma unroll
        for (int fm = 0; fm < 2; ++fm)
            af[fm] = *(const bf16x8*)&As[wm*32 + fm*16 + (lane&15)][colr];
#pragma unroll
        for (int g = 0; g < 3; ++g) {
            const int gi = (g == 2) ? GN : g;
#pragma unroll
            for (int fn = 0; fn < 2; ++fn) {
                const bf16x8 bv = *(const bf16x8*)&Bs[g*64 + wn*32 + fn*16 + (lane&15)][colr];
#pragma unroll
                for (int fm = 0; fm < 2; ++fm)
                    acc[gi][fm][fn] = __builtin_amdgcn_mfma_f32_16x16x32_bf16(
                        af[fm], bv, acc[gi][fm][fn], 0, 0, 0);
            }
        }
    }
}

template<bool HAS_H>
__global__ __launch_bounds__(256, 4) void gru2_kernel(
    const ushort* __restrict__ X0, const ushort* __restrict__ X1,
    const ushort* __restrict__ Hb0, const ushort* __restrict__ Hb1,
    const ushort* __restrict__ Wih0, const ushort* __restrict__ Wih1,
    const ushort* __restrict__ Whh0, const ushort* __restrict__ Whh1,
    const float* __restrict__ bih0, const float* __restrict__ bih1,
    const float* __restrict__ bhh0, const float* __restrict__ bhh1,
    ushort* __restrict__ HoutB0, ushort* __restrict__ HoutB1,
    ushort* __restrict__ emb0, ushort* __restrict__ emb1)
{
    __shared__ __align__(16) ushort As[BM][BK];   // 8 KB
    __shared__ __align__(16) ushort Bs[192][BK];  // 24 KB

    const int sel = blockIdx.z;
    const ushort* Xb   = sel ? X1 : X0;
    const ushort* Hb   = sel ? Hb1 : Hb0;
    const ushort* Wihb = sel ? Wih1 : Wih0;
    const ushort* Whhb = sel ? Whh1 : Whh0;
    const float*  bih  = sel ? bih1 : bih0;
    const float*  bhh  = sel ? bhh1 : bhh0;
    ushort* Hout_b = sel ? HoutB1 : HoutB0;
    ushort* emb_b  = sel ? emb1 : emb0;

    const int tid = threadIdx.x;
    const int lane = tid & 63, wid = tid >> 6;
    const int wm = wid >> 1, wn = wid & 1;

    // XCD remap: flat = ((ib/8)*4 + jb)*8 + ib%8  (bijective on [0,1024))
    const int flat = blockIdx.x;
    const int i8   = flat & 7;
    const int rest = flat >> 3;
    const int jb   = rest & 3;
    const int ib   = (rest >> 2) * 8 + i8;
    const int i0 = ib * BM;
    const int j0 = jb * BNG;

    const int csw  = (((lane & 7) ^ (lane >> 3)) * 8);
    const int rsub = lane >> 3;

    // fixed wave-uniform LDS destinations
    ushort* const ldsA0 = &As[0][0] + (size_t)wid*512;
    ushort* const ldsA1 = &As[0][0] + (size_t)(wid+4)*512;
    ushort* ldsB[6];
#pragma unroll
    for (int s = 0; s < 6; ++s) ldsB[s] = &Bs[0][0] + (size_t)(wid + 4*s)*512;

    f32x4 acc[4][2][2] = {};   // [r,z,n_ih | n_hh][fm][fn]

    // ---- phase 1: X @ Wih^T ----
    {
        const ushort* ga0 = Xb + (size_t)(i0 + wid*8     + rsub)*H_ + csw;
        const ushort* ga1 = Xb + (size_t)(i0 + (wid+4)*8 + rsub)*H_ + csw;
        const ushort* gb[6];
#pragma unroll
        for (int s = 0; s < 6; ++s) {
            const int rowB = (wid + 4*s)*8 + rsub;
            gb[s] = Wihb + (size_t)((rowB>>6)*Hh_ + j0 + (rowB&63))*H_ + csw;
        }
        for (int k0 = 0; k0 < H_; k0 += BK) {
            gload16(ga0, ldsA0);
            gload16(ga1, ldsA1);
#pragma unroll
            for (int s = 0; s < 6; ++s) gload16(gb[s], ldsB[s]);
            ga0 += BK; ga1 += BK;
#pragma unroll
            for (int s = 0; s < 6; ++s) gb[s] += BK;
            __syncthreads();
            compute_tile64<2>(acc, As, Bs, lane, wm, wn);
            __syncthreads();
        }
    }
    // ---- phase 2: H @ Whh^T ----
    if (HAS_H) {
        const ushort* ga0 = Hb + (size_t)(i0 + wid*8     + rsub)*Hh_ + csw;
        const ushort* ga1 = Hb + (size_t)(i0 + (wid+4)*8 + rsub)*Hh_ + csw;
        const ushort* gb[6];
#pragma unroll
        for (int s = 0; s < 6; ++s) {
            const int rowB = (wid + 4*s)*8 + rsub;
            gb[s] = Whhb + (size_t)((rowB>>6)*Hh_ + j0 + (rowB&63))*Hh_ + csw;
        }
        for (int k0 = 0; k0 < Hh_; k0 += BK) {
            gload16(ga0, ldsA0);
            gload16(ga1, ldsA1);
#pragma unroll
            for (int s = 0; s < 6; ++s) gload16(gb[s], ldsB[s]);
            ga0 += BK; ga1 += BK;
#pragma unroll
            for (int s = 0; s < 6; ++s) gb[s] += BK;
            __syncthreads();
            compute_tile64<3>(acc, As, Bs, lane, wm, wn);
            __syncthreads();
        }
    }

    // ---- epilogue: gates -> padded LDS tile -> coalesced store ----
    // K-loop ends with __syncthreads(): LDS is reusable.
    ushort (*Cs)[72] = reinterpret_cast<ushort (*)[72]>(&Bs[0][0]);  // 64x72 = 9 KB

#pragma unroll
    for (int fn = 0; fn < 2; ++fn) {
        const int lc = wn*32 + fn*16 + (lane & 15);   // local col
        const int j = j0 + lc;
        const float bri = bih[j],       brh = bhh[j];
        const float bzi = bih[Hh_ + j], bzh = bhh[Hh_ + j];
        const float bni = bih[2*Hh_+j], bnh = bhh[2*Hh_ + j];
#pragma unroll
        for (int fm = 0; fm < 2; ++fm) {
#pragma unroll
            for (int r = 0; r < 4; ++r) {
                const int lr = wm*32 + fm*16 + (lane >> 4)*4 + r;  // local row
                const int i = i0 + lr;
                const float xr = acc[0][fm][fn][r] + bri + brh;
                const float xz = acc[1][fm][fn][r] + bzi + bzh;
                const float xn = acc[2][fm][fn][r] + bni;
                float hn = bnh, hprev = 0.f;
                if (HAS_H) { hn += acc[3][fm][fn][r]; hprev = bf2f(Hb[(size_t)i*Hh_ + j]); }
                const float rg = sigmoidf_(xr);
                const float zg = sigmoidf_(xz);
                const float ng = tanhf_(xn + rg * hn);
                const float hp = (1.f - zg) * ng + zg * hprev;
                Cs[lr][lc] = f2bf(HAS_H ? 0.5f * (hprev + hp) : hp);
            }
        }
    }
    __syncthreads();

    {
        ushort* const dst_base = HAS_H ? emb_b : Hout_b;
        const int ldst = HAS_H ? H_ : Hh_;
        const int seg = tid & 7;          // 16B segment within the 128B row
#pragma unroll
        for (int q = 0; q < 2; ++q) {
            const int row = q*32 + (tid >> 3);
            const bf16x8 v = *(const bf16x8*)&Cs[row][seg*8];
            *(bf16x8*)(dst_base + (size_t)(i0+row)*ldst + j0 + seg*8) = v;
        }
    }
}

// ---------------------------------------------------------------------------
// block reductions
// ---------------------------------------------------------------------------
template<int NT>
__device__ __forceinline__ float block_reduce_max(float v, float* red) {
#pragma unroll
    for (int o = 32; o > 0; o >>= 1) v = fmaxf(v, __shfl_down(v, o));
    const int wid = threadIdx.x >> 6;
    if ((threadIdx.x & 63) == 0) red[wid] = v;
    __syncthreads();
    if (threadIdx.x == 0) {
        float m = red[0];
#pragma unroll
        for (int i = 1; i < NT/64; ++i) m = fmaxf(m, red[i]);
        red[0] = m;
    }
    __syncthreads();
    const float r = red[0];
    __syncthreads();
    return r;
}

template<int NT>
__device__ __forceinline__ float block_reduce_sum(float v, float* red) {
#pragma unroll
    for (int o = 32; o > 0; o >>= 1) v += __shfl_down(v, o);
    const int wid = threadIdx.x >> 6;
    if ((threadIdx.x & 63) == 0) red[wid] = v;
    __syncthreads();
    if (threadIdx.x == 0) {
        float m = red[0];
#pragma unroll
        for (int i = 1; i < NT/64; ++i) m += red[i];
        red[0] = m;
    }
    __syncthreads();
    const float r = red[0];
    __syncthreads();
    return r;
}

// ---------------------------------------------------------------------------
// attention.
// A: logits.  grid (16, T), 256 threads: 64 u/block, 4 threads per u.
// ---------------------------------------------------------------------------
__global__ __launch_bounds__(256) void attn_logits_kernel(
    const ushort* __restrict__ db, const float* __restrict__ key,
    const int* __restrict__ attn_mask, float* __restrict__ alog)
{
    const int t = blockIdx.y;
    const int tid = threadIdx.x;
    const int u = blockIdx.x*64 + (tid >> 2);
    const int kq = (tid & 3) * 128;

    const bf16x8* r8 = (const bf16x8*)(db + ((size_t)t*U_ + u)*H_ + kq);
    const float* kp = key + t*H_ + kq;
    float s = 0.f;
#pragma unroll
    for (int k8 = 0; k8 < 16; ++k8) {
        const bf16x8 v = r8[k8];
#pragma unroll
        for (int j = 0; j < 8; ++j)
            s = fmaf(kp[k8*8 + j], bf2f((ushort)v[j]), s);
    }
    s += __shfl_xor(s, 1);
    s += __shfl_xor(s, 2);
    if ((tid & 3) == 0)
        alog[t*U_ + u] = attn_mask[t*U_ + u] ? s : -1e9f;
}

// B: weighted sum partials with INLINE softmax.
// grid (8, T), 512 threads = 8 u-slices x 64 h-octets.
__global__ __launch_bounds__(512) void attn_wsum_kernel(
    const ushort* __restrict__ db, const float* __restrict__ alog,
    float* __restrict__ part)
{
    __shared__ float sred[8][64][8];   // 16 KB
    __shared__ float red[8];
    const int t = blockIdx.y, u0 = blockIdx.x * 128;
    const int tid = threadIdx.x;

    const float v0 = alog[t*U_ + tid], v1 = alog[t*U_ + tid + 512];
    const float m = block_reduce_max<512>(fmaxf(v0, v1), red);
    const float ssum = block_reduce_sum<512>(__expf(v0 - m) + __expf(v1 - m), red);
    const float inv = 1.f / ssum;

    const int usub = tid >> 6;   // 0..7
    const int h8   = tid & 63;   // 0..63

    float a[8] = {};
    for (int uu = 0; uu < 16; ++uu) {
        const int u = u0 + usub*16 + uu;
        const float w = __expf(alog[t*U_ + u] - m) * inv;
        const bf16x8 v = *(const bf16x8*)(db + ((size_t)t*U_ + u)*H_ + h8*8);
#pragma unroll
        for (int j = 0; j < 8; ++j) a[j] = fmaf(w, bf2f((ushort)v[j]), a[j]);
    }
#pragma unroll
    for (int j = 0; j < 8; ++j) sred[usub][h8][j] = a[j];
    __syncthreads();

    const int h8r = tid >> 3;    // 0..63
    const int cr  = tid & 7;     // 0..7
    float s = 0.f;
#pragma unroll
    for (int us = 0; us < 8; ++us) s += sred[us][h8r][cr];
    part[((size_t)blockIdx.x*T_ + t)*H_ + h8r*8 + cr] = s;
}

// ---------------------------------------------------------------------------
// feature = finf + sum(part) -> bf16
// ---------------------------------------------------------------------------
__global__ __launch_bounds__(256) void featcvt_kernel(
    const float* __restrict__ finf, const float* __restrict__ part,
    ushort* __restrict__ featb)
{
    const int row = blockIdx.x;       // t*64+l
    const int t = row >> 6;
    const int h = threadIdx.x * 2;
    const float2 v = *(const float2*)(finf + (size_t)row*H_ + h);
    float ax = 0.f, ay = 0.f;
#pragma unroll
    for (int p = 0; p < 8; ++p) {
        const float2 a = *(const float2*)(part + ((size_t)p*T_ + t)*H_ + h);
        ax += a.x; ay += a.y;
    }
    ushort2 o; o.x = f2bf(v.x + ax); o.y = f2bf(v.y + ay);
    *(ushort2*)(featb + (size_t)row*H_ + h) = o;
}

// ---------------------------------------------------------------------------
// ff = tanh(featb @ Wb^T + bb) -> bf16.  M=1024, N=512, K=512. Swizzled LDS.
// ---------------------------------------------------------------------------
__global__ __launch_bounds__(256) void ffgemm_kernel(
    const ushort* __restrict__ featb, const ushort* __restrict__ Wbb,
    const float* __restrict__ bb, ushort* __restrict__ ffb)
{
    __shared__ __align__(16) ushort As[128][BK];  // 16 KB
    __shared__ __align__(16) ushort Bs[64][BK];   // 8 KB

    const int tid = threadIdx.x;
    const int lane = tid & 63, wid = tid >> 6;
    const int wm = wid >> 1, wn = wid & 1;
    const int i0 = blockIdx.y * 128;
    const int j0 = blockIdx.x * 64;
    const int csw  = (((lane & 7) ^ (lane >> 3)) * 8);
    const int rsub = lane >> 3;

    f32x4 acc[4][2] = {};

    for (int k0 = 0; k0 < H_; k0 += BK) {
#pragma unroll
        for (int cc = wid; cc < 24; cc += 4) {
            if (cc < 16) {
                const ushort* g = featb + (size_t)(i0 + cc*8 + rsub)*H_ + k0 + csw;
                gload16(g, &As[0][0] + cc*512);
            } else {
                const int c = cc - 16;
                const ushort* g = Wbb + (size_t)(j0 + c*8 + rsub)*H_ + k0 + csw;
                gload16(g, &Bs[0][0] + c*512);
            }
        }
        __syncthreads();
#pragma unroll
        for (int s = 0; s < 2; ++s) {
            const int colr = (((s*4 + (lane>>4)) ^ (lane & 7)) * 8);
            bf16x8 af[4];
#pragma unroll
            for (int fm = 0; fm < 4; ++fm)
                af[fm] = *(const bf16x8*)&As[wm*64 + fm*16 + (lane&15)][colr];
#pragma unroll
            for (int fn = 0; fn < 2; ++fn) {
                const bf16x8 bv = *(const bf16x8*)&Bs[wn*32 + fn*16 + (lane&15)][colr];
#pragma unroll
                for (int fm = 0; fm < 4; ++fm)
                    acc[fm][fn] = __builtin_amdgcn_mfma_f32_16x16x32_bf16(
                        af[fm], bv, acc[fm][fn], 0, 0, 0);
            }
        }
        __syncthreads();
    }

#pragma unroll
    for (int fn = 0; fn < 2; ++fn) {
        const int j = j0 + wn*32 + fn*16 + (lane & 15);
        const float b = bb[j];
#pragma unroll
        for (int fm = 0; fm < 4; ++fm)
#pragma unroll
            for (int r = 0; r < 4; ++r) {
                const int i = i0 + wm*64 + fm*16 + (lane >> 4)*4 + r;
                ffb[(size_t)i*H_ + j] = f2bf(tanhf_(acc[fm][fn][r] + b));
            }
    }
}

// ---------------------------------------------------------------------------
// logits[t*64+l, n] = ff[t*64+l,:] . V[n,:].  Swizzled LDS.
// ---------------------------------------------------------------------------
__global__ __launch_bounds__(256) void logits_kernel(
    const ushort* __restrict__ ffb, const ushort* __restrict__ dbb,
    const ushort* __restrict__ Kembb, float* __restrict__ logits)
{
    __shared__ __align__(16) ushort As[64][BK];   // 8 KB
    __shared__ __align__(16) ushort Bs[64][BK];   // 8 KB

    const int tid = threadIdx.x;
    const int lane = tid & 63, wid = tid >> 6;
    const int t = blockIdx.y;
    const int bx = blockIdx.x;
    const bool kw = (bx == 16);
    const int csw  = (((lane & 7) ^ (lane >> 3)) * 8);
    const int rsub = lane >> 3;

    f32x4 acc[4] = {};

    for (int k0 = 0; k0 < H_; k0 += BK) {
#pragma unroll
        for (int cc = wid; cc < 16; cc += 4) {
            if (cc < 8) {
                const ushort* g = ffb + (size_t)(t*64 + cc*8 + rsub)*H_ + k0 + csw;
                gload16(g, &As[0][0] + cc*512);
            } else {
                const int rloc = (cc-8)*8 + rsub;
                const ushort* g = kw ? (Kembb + (size_t)rloc*H_ + k0 + csw)
                                     : (dbb + (size_t)(t*U_ + bx*64 + rloc)*H_ + k0 + csw);
                gload16(g, &Bs[0][0] + (cc-8)*512);
            }
        }
        __syncthreads();
#pragma unroll
        for (int s = 0; s < 2; ++s) {
            const int colr = (((s*4 + (lane>>4)) ^ (lane & 7)) * 8);
            const bf16x8 af = *(const bf16x8*)&As[wid*16 + (lane&15)][colr];
#pragma unroll
            for (int fn = 0; fn < 4; ++fn) {
                const bf16x8 bv = *(const bf16x8*)&Bs[fn*16 + (lane&15)][colr];
                acc[fn] = __builtin_amdgcn_mfma_f32_16x16x32_bf16(af, bv, acc[fn], 0, 0, 0);
            }
        }
        __syncthreads();
    }

    const int ncols = U_ + K_;
#pragma unroll
    for (int fn = 0; fn < 4; ++fn) {
        const int jg = (kw ? U_ : bx*64) + fn*16 + (lane & 15);
#pragma unroll
        for (int r = 0; r < 4; ++r) {
            const int i = t*64 + wid*16 + (lane >> 4)*4 + r;
            logits[(size_t)i*ncols + jg] = acc[fn][r];
        }
    }
}

// ---------------------------------------------------------------------------
// per-row log_softmax over 1088 logits
// ---------------------------------------------------------------------------
__global__ __launch_bounds__(256) void lsm_kernel(
    const float* __restrict__ logits, float* __restrict__ out)
{
    __shared__ float sl[U_ + K_];
    __shared__ float red[4];
    const int row = blockIdx.x;
    const int tid = threadIdx.x;
    const int ncols = U_ + K_;

    float m = -3.4e38f;
    for (int idx = tid; idx < ncols; idx += 256) {
        const float v = logits[(size_t)row*ncols + idx];
        sl[idx] = v;
        m = fmaxf(m, v);
    }
    __syncthreads();
    m = block_reduce_max<256>(m, red);

    float s = 0.f;
    for (int idx = tid; idx < ncols; idx += 256) s += __expf(sl[idx] - m);
    s = block_reduce_sum<256>(s, red);
    const float lse = m + __logf(s);

    for (int idx = tid; idx < ncols; idx += 256)
        out[(size_t)row*ncols + idx] = sl[idx] - lse;
}

// ---------------------------------------------------------------------------
extern "C" void kernel_launch(void* const* d_in, const int* in_sizes, int n_in,
                              void* d_out, int out_size, void* d_ws, size_t ws_size,
                              hipStream_t stream)
{
    const float* feat  = (const float*)d_in[0];
    const float* key   = (const float*)d_in[1];
    const float* finf  = (const float*)d_in[2];
    const float* Wih_f = (const float*)d_in[3];
    const float* Whh_f = (const float*)d_in[4];
    const float* bih_f = (const float*)d_in[5];
    const float* bhh_f = (const float*)d_in[6];
    const float* Wih_b = (const float*)d_in[7];
    const float* Whh_b = (const float*)d_in[8];
    const float* bih_b = (const float*)d_in[9];
    const float* bhh_b = (const float*)d_in[10];
    const float* Wb    = (const float*)d_in[11];
    const float* bb    = (const float*)d_in[12];
    const float* Kemb  = (const float*)d_in[13];
    const int* col_idx  = (const int*)d_in[14];
    const int* col_mask = (const int*)d_in[15];
    const int* tab_idx  = (const int*)d_in[16];
    const int* tab_mask = (const int*)d_in[17];
    const int* attn_mask= (const int*)d_in[18];
    float* out = (float*)d_out;

    char* p = (char*)d_ws;
    ushort* wbf  = (ushort*)p;  p += (size_t)(2*(S0_+S1_) + WB_ + KE_)*2;  // 2.95 MB
    ushort* x1b  = (ushort*)p;  p += (size_t)M_*H_*2;                      // 16.8 MB
    ushort* x2b  = (ushort*)p;  p += (size_t)M_*H_*2;
    ushort* f1b  = (ushort*)p;  p += (size_t)M_*Hh_*2;
    ushort* b1b  = (ushort*)p;  p += (size_t)M_*Hh_*2;
    ushort* dbb  = (ushort*)p;  p += (size_t)M_*H_*2;                      // 16.8 MB
    float*  alog = (float*)p;   p += (size_t)T_*U_*4;
    float*  part = (float*)p;   p += (size_t)8*T_*H_*4;
    ushort* featb= (ushort*)p;  p += (size_t)T_*L_*H_*2;
    ushort* ffb  = (ushort*)p;  p += (size_t)T_*L_*H_*2;
    float*  lg   = (float*)p;   p += (size_t)T_*L_*(U_+K_)*4;              // 4.45 MB

    const ushort* Wihf_b = wbf;
    const ushort* Whhf_b = wbf + S0_;
    const ushort* Wihb_b = wbf + S0_ + S1_;
    const ushort* Whhb_b = wbf + 2*S0_ + S1_;
    const ushort* Wbb    = wbf + 2*(S0_ + S1_);
    const ushort* Kembb  = wbf + 2*(S0_ + S1_) + WB_;

    pre_kernel<<<NWCVT_ + (U_/2)*T_, 256, 0, stream>>>(
        Wih_f, Whh_f, Wih_b, Whh_b, Wb, Kemb, wbf,
        feat, col_idx, col_mask, tab_idx, tab_mask, x1b, x2b);

    dim3 gg((M_/BM)*(Hh_/BNG), 1, 2);   // (1024, 1, 2), XCD-remapped in-kernel
    gru2_kernel<false><<<gg, 256, 0, stream>>>(
        x1b, x2b, nullptr, nullptr,
        Wihf_b, Wihb_b, Whhf_b, Whhb_b, bih_f, bih_b, bhh_f, bhh_b,
        f1b, b1b, nullptr, nullptr);
    gru2_kernel<true><<<gg, 256, 0, stream>>>(
        x2b, x1b, f1b, b1b,
        Wihf_b, Wihb_b, Whhf_b, Whhb_b, bih_f, bih_b, bhh_f, bhh_b,
        nullptr, nullptr, dbb, dbb + Hh_);

    attn_logits_kernel<<<dim3(16, T_), 256, 0, stream>>>(dbb, key, attn_mask, alog);
    attn_wsum_kernel<<<dim3(8, T_), 512, 0, stream>>>(dbb, alog, part);
    featcvt_kernel<<<T_*L_, 256, 0, stream>>>(finf, part, featb);
    ffgemm_kernel<<<dim3(H_/64, (T_*L_)/128), 256, 0, stream>>>(featb, Wbb, bb, ffb);
    logits_kernel<<<dim3(17, T_), 256, 0, stream>>>(ffb, dbb, Kembb, lg);
    lsm_kernel<<<T_*L_, 256, 0, stream>>>(lg, out);
}